// Round 1
// baseline (958.106 us; speedup 1.0000x reference)
//
#include <hip/hip_runtime.h>
#include <hip/hip_bf16.h>
#include <math.h>

#define EPSF 1e-5f

// ---------------------------------------------------------------------------
// LN over channel dim (C=256) of [B,256,32,32]. Single pass over x:
// block = 256 thr = 32 positions x 8 channel-groups(32ch each).
// grid = B*N/32 = 256 blocks.
// ---------------------------------------------------------------------------
__global__ __launch_bounds__(256) void ln_kernel(
    const float* __restrict__ x, const float* __restrict__ gamma,
    const float* __restrict__ beta, float* __restrict__ out) {
  __shared__ float s_sum[8][32];
  __shared__ float s_sq[8][32];
  int t = threadIdx.x;
  int nl = t & 31, cg = t >> 5;
  int p0 = blockIdx.x * 32;  // global position base (b*1024 + n0)
  int b = p0 >> 10;
  int n = (p0 & 1023) + nl;
  const float* xp = x + ((size_t)b * 256 + cg * 32) * 1024 + n;
  float v[32];
  float sum = 0.f, sq = 0.f;
#pragma unroll
  for (int i = 0; i < 32; ++i) {
    float val = xp[(size_t)i * 1024];
    v[i] = val;
    sum += val;
    sq += val * val;
  }
  s_sum[cg][nl] = sum;
  s_sq[cg][nl] = sq;
  __syncthreads();
  float ts = 0.f, tq = 0.f;
#pragma unroll
  for (int g = 0; g < 8; ++g) {
    ts += s_sum[g][nl];
    tq += s_sq[g][nl];
  }
  float mu = ts * (1.f / 256.f);
  float var = tq * (1.f / 256.f) - mu * mu;
  float rs = rsqrtf(var + EPSF);
  float* op = out + ((size_t)b * 256 + cg * 32) * 1024 + n;
#pragma unroll
  for (int i = 0; i < 32; ++i) {
    int c = cg * 32 + i;
    op[(size_t)i * 1024] = (v[i] - mu) * rs * gamma[c] + beta[c];
  }
}

// ---------------------------------------------------------------------------
// Generic 1x1-conv GEMM: out[b,o,n] = epilogue( sum_c W[o,c] * X[b,c,n] ).
// Block = 256 thr; covers 64 n x 64 o. Grid = B * 16(ntiles) * OT(otiles).
// X tile staged in LDS. W rows are wave-uniform -> broadcast loads.
// ---------------------------------------------------------------------------
template <int KD_>
__global__ __launch_bounds__(256) void gemm_kernel(
    const float* __restrict__ X,    // [B, KD_, 1024]
    const float* __restrict__ W,    // [OC, KD_]
    const float* __restrict__ bn,   // [4, OC] or null
    const float* __restrict__ bias, // [OC] or null
    const float* __restrict__ add1, // [B, OC, 1024] or null
    const float* __restrict__ add2, // [B, OC, 1024] or null
    float* __restrict__ out,        // [B, OC, 1024]
    int OC, int OT) {
  __shared__ float xt[KD_][64];
  int bx = blockIdx.x;
  int ot = bx % OT;
  int nt = (bx / OT) & 15;
  int b = bx / (OT * 16);
  int t = threadIdx.x;
  int n0 = nt * 64;
  const float* Xb = X + (size_t)b * KD_ * 1024 + n0;
  for (int i = t; i < KD_ * 64; i += 256) {
    int c = i >> 6, j = i & 63;
    xt[c][j] = Xb[(size_t)c * 1024 + j];
  }
  __syncthreads();
  int lane = t & 63, w = t >> 6;
  int o_base = ot * 64;
  for (int oo = 0; oo < 16; ++oo) {
    int o = o_base + w + oo * 4;
    if (o >= OC) break;  // wave-uniform
    const float* Wr = W + (size_t)o * KD_;
    float a0 = 0.f, a1 = 0.f, a2 = 0.f, a3 = 0.f;
    int c = 0;
    for (; c + 3 < KD_; c += 4) {
      a0 += Wr[c] * xt[c][lane];
      a1 += Wr[c + 1] * xt[c + 1][lane];
      a2 += Wr[c + 2] * xt[c + 2][lane];
      a3 += Wr[c + 3] * xt[c + 3][lane];
    }
    for (; c < KD_; ++c) a0 += Wr[c] * xt[c][lane];
    float r = (a0 + a1) + (a2 + a3);
    if (bn) {
      float g = bn[o], bb = bn[OC + o], m = bn[2 * OC + o], vv = bn[3 * OC + o];
      r = (r - m) * (g * rsqrtf(vv + EPSF)) + bb;
    }
    if (bias) r += bias[o];
    size_t idx = ((size_t)b * OC + o) * 1024 + n0 + lane;
    if (add1) r += add1[idx];
    if (add2) r += add2[idx];
    out[idx] = r;
  }
}

// ---------------------------------------------------------------------------
// Attention: per (b,h): S = (Q^T K)*0.25, softmax over m, O = V @ P^T.
// One thread per query n. K (16x1024) staged in LDS; V read as uniform
// float4 global loads (L2-resident). Two passes: rowmax, then exp+PV.
// grid = B*NH*4 = 256 blocks of 256 thr.
// ---------------------------------------------------------------------------
__global__ __launch_bounds__(256) void attn_kernel(
    const float* __restrict__ qkv, float* __restrict__ o) {
  __shared__ float kt[16][1024];
  int blk = blockIdx.x;
  int ntile = blk & 3;
  int h = (blk >> 2) & 7;
  int b = blk >> 5;
  const float* base = qkv + ((size_t)b * 512 + h * 64) * 1024;
  int t = threadIdx.x;
  for (int i = t; i < 16 * 1024; i += 256) {
    kt[i >> 10][i & 1023] = base[16 * 1024 + i];
  }
  __syncthreads();
  int n = ntile * 256 + t;
  float q[16];
#pragma unroll
  for (int k = 0; k < 16; ++k) q[k] = base[(size_t)k * 1024 + n] * 0.25f;
  // pass 1: row max
  float mx = -1e30f;
  for (int m4 = 0; m4 < 256; ++m4) {
    float s0 = 0.f, s1 = 0.f, s2 = 0.f, s3 = 0.f;
#pragma unroll
    for (int k = 0; k < 16; ++k) {
      const float4 kv = *reinterpret_cast<const float4*>(&kt[k][m4 * 4]);
      s0 += q[k] * kv.x;
      s1 += q[k] * kv.y;
      s2 += q[k] * kv.z;
      s3 += q[k] * kv.w;
    }
    mx = fmaxf(mx, fmaxf(fmaxf(s0, s1), fmaxf(s2, s3)));
  }
  // pass 2: exp-sum + PV accumulate
  const float* V = base + 32 * 1024;
  float acc[32];
#pragma unroll
  for (int d = 0; d < 32; ++d) acc[d] = 0.f;
  float se = 0.f;
  for (int m4 = 0; m4 < 256; ++m4) {
    float s0 = 0.f, s1 = 0.f, s2 = 0.f, s3 = 0.f;
#pragma unroll
    for (int k = 0; k < 16; ++k) {
      const float4 kv = *reinterpret_cast<const float4*>(&kt[k][m4 * 4]);
      s0 += q[k] * kv.x;
      s1 += q[k] * kv.y;
      s2 += q[k] * kv.z;
      s3 += q[k] * kv.w;
    }
    float p0 = __expf(s0 - mx), p1 = __expf(s1 - mx);
    float p2 = __expf(s2 - mx), p3 = __expf(s3 - mx);
    se += (p0 + p1) + (p2 + p3);
#pragma unroll
    for (int d = 0; d < 32; ++d) {
      const float4 vv = *reinterpret_cast<const float4*>(&V[(size_t)d * 1024 + m4 * 4]);
      acc[d] += p0 * vv.x + p1 * vv.y + p2 * vv.z + p3 * vv.w;
    }
  }
  float inv = 1.f / se;
  float* op = o + ((size_t)b * 256 + h * 32) * 1024 + n;
#pragma unroll
  for (int d = 0; d < 32; ++d) op[(size_t)d * 1024] = acc[d] * inv;
}

// ---------------------------------------------------------------------------
// PE: o += bn(dwconv3x3(v_img, pe_w), pe_bn). v_img channel c -> qkv row
// (c/32)*64 + 32 + (c%32). One thread per output element.
// ---------------------------------------------------------------------------
__global__ __launch_bounds__(256) void pe_kernel(
    const float* __restrict__ qkv, const float* __restrict__ pe_w,
    const float* __restrict__ pe_bn, float* __restrict__ o) {
  int idx = blockIdx.x * 256 + threadIdx.x;  // [0, B*256*1024)
  int n = idx & 1023;
  int c = (idx >> 10) & 255;
  int b = idx >> 18;
  int y = n >> 5, xx = n & 31;
  int head = c >> 5, d = c & 31;
  const float* v = qkv + ((size_t)b * 512 + head * 64 + 32 + d) * 1024;
  const float* wp = pe_w + c * 9;
  float s = 0.f;
#pragma unroll
  for (int dy = -1; dy <= 1; ++dy) {
    int yy = y + dy;
    if (yy < 0 || yy > 31) continue;
#pragma unroll
    for (int dx = -1; dx <= 1; ++dx) {
      int xw = xx + dx;
      if (xw < 0 || xw > 31) continue;
      s += wp[(dy + 1) * 3 + (dx + 1)] * v[yy * 32 + xw];
    }
  }
  float g = pe_bn[c], bb = pe_bn[256 + c], m = pe_bn[512 + c],
        var = pe_bn[768 + c];
  s = (s - m) * (g * rsqrtf(var + EPSF)) + bb;
  o[idx] += s;
}

// ---------------------------------------------------------------------------
// CGLU inner: act = gelu_exact(dwconv3x3(a, dw_w) + dw_b) * g,
// a = h[:, :170], g = h[:, 170:]. One thread per element of [B,170,1024].
// ---------------------------------------------------------------------------
__global__ __launch_bounds__(256) void glu_kernel(
    const float* __restrict__ h, const float* __restrict__ dw_w,
    const float* __restrict__ dw_b, float* __restrict__ act) {
  int idx = blockIdx.x * 256 + threadIdx.x;
  if (idx >= 8 * 170 * 1024) return;
  int n = idx & 1023;
  int cn = idx >> 10;  // b*170 + cc
  int cc = cn % 170;
  int b = cn / 170;
  int y = n >> 5, xx = n & 31;
  const float* a = h + ((size_t)b * 340 + cc) * 1024;
  const float* g = h + ((size_t)b * 340 + 170 + cc) * 1024;
  const float* wp = dw_w + cc * 9;
  float s = dw_b[cc];
#pragma unroll
  for (int dy = -1; dy <= 1; ++dy) {
    int yy = y + dy;
    if (yy < 0 || yy > 31) continue;
#pragma unroll
    for (int dx = -1; dx <= 1; ++dx) {
      int xw = xx + dx;
      if (xw < 0 || xw > 31) continue;
      s += wp[(dy + 1) * 3 + (dx + 1)] * a[yy * 32 + xw];
    }
  }
  float ge = 0.5f * s * (1.f + erff(s * 0.70710678118654752f));
  act[idx] = ge * g[n];
}

// ---------------------------------------------------------------------------
extern "C" void kernel_launch(void* const* d_in, const int* in_sizes, int n_in,
                              void* d_out, int out_size, void* d_ws,
                              size_t ws_size, hipStream_t stream) {
  const float* x      = (const float*)d_in[0];
  const float* ln1_g  = (const float*)d_in[1];
  const float* ln1_b  = (const float*)d_in[2];
  const float* ln2_g  = (const float*)d_in[3];
  const float* ln2_b  = (const float*)d_in[4];
  const float* qkv_w  = (const float*)d_in[5];
  const float* qkv_bn = (const float*)d_in[6];
  const float* pe_w   = (const float*)d_in[7];
  const float* pe_bn  = (const float*)d_in[8];
  const float* proj_w = (const float*)d_in[9];
  const float* proj_bn= (const float*)d_in[10];
  const float* fc1_w  = (const float*)d_in[11];
  const float* fc1_b  = (const float*)d_in[12];
  const float* dw_w   = (const float*)d_in[13];
  const float* dw_b   = (const float*)d_in[14];
  const float* fc2_w  = (const float*)d_in[15];
  const float* fc2_b  = (const float*)d_in[16];

  float* ws = (float*)d_ws;
  const size_t M = 1024 * 1024;
  float* xn   = ws;           // 2M floats, reused later by act (1.36M)
  float* qkvb = ws + 2 * M;   // 4M floats, reused later by hb (2.72M)
  float* ob   = ws + 6 * M;   // 2M floats
  float* x1   = ws + 8 * M;   // 2M floats
  float* xn2  = ws + 10 * M;  // 2M floats
  float* hb   = qkvb;         // fc1 out [B,340,1024]
  float* act  = xn;           // [B,170,1024]
  float* outp = (float*)d_out;

  // 1. xn = LN1(x)
  hipLaunchKernelGGL(ln_kernel, dim3(256), dim3(256), 0, stream, x, ln1_g,
                     ln1_b, xn);
  // 2. qkv = BN(qkv_w @ xn)   [B,512,1024]
  hipLaunchKernelGGL((gemm_kernel<256>), dim3(8 * 16 * 8), dim3(256), 0,
                     stream, xn, qkv_w, qkv_bn, nullptr, nullptr, nullptr,
                     qkvb, 512, 8);
  // 3. ob = attention(qkv)    [B,256,1024]
  hipLaunchKernelGGL(attn_kernel, dim3(256), dim3(256), 0, stream, qkvb, ob);
  // 4. ob += BN(dwconv3x3(v))
  hipLaunchKernelGGL(pe_kernel, dim3(8192), dim3(256), 0, stream, qkvb, pe_w,
                     pe_bn, ob);
  // 5. x1 = x + BN(proj_w @ ob)
  hipLaunchKernelGGL((gemm_kernel<256>), dim3(8 * 16 * 4), dim3(256), 0,
                     stream, ob, proj_w, proj_bn, nullptr, x, nullptr, x1, 256,
                     4);
  // 6. xn2 = LN2(x1)
  hipLaunchKernelGGL(ln_kernel, dim3(256), dim3(256), 0, stream, x1, ln2_g,
                     ln2_b, xn2);
  // 7. hb = fc1_w @ xn2 + fc1_b    [B,340,1024]
  hipLaunchKernelGGL((gemm_kernel<256>), dim3(8 * 16 * 6), dim3(256), 0,
                     stream, xn2, fc1_w, nullptr, fc1_b, nullptr, nullptr, hb,
                     340, 6);
  // 8. act = gelu(dwconv(a)+dw_b) * g
  hipLaunchKernelGGL(glu_kernel, dim3(5440), dim3(256), 0, stream, hb, dw_w,
                     dw_b, act);
  // 9. out = x1 + xn2 + fc2_w @ act + fc2_b
  hipLaunchKernelGGL((gemm_kernel<170>), dim3(8 * 16 * 4), dim3(256), 0,
                     stream, act, fc2_w, nullptr, fc2_b, x1, xn2, outp, 256,
                     4);
}

// Round 2
// 826.934 us; speedup vs baseline: 1.1586x; 1.1586x over previous
//
#include <hip/hip_runtime.h>
#include <hip/hip_bf16.h>
#include <math.h>

#define EPSF 1e-5f

using short8 = __attribute__((ext_vector_type(8))) short;
using f32x4 = __attribute__((ext_vector_type(4))) float;

// ---------------------------------------------------------------------------
// LN over channel dim (C=256) of [B,256,32,32]. Single pass over x:
// block = 256 thr = 32 positions x 8 channel-groups(32ch each).
// grid = B*N/32 = 256 blocks.
// ---------------------------------------------------------------------------
__global__ __launch_bounds__(256) void ln_kernel(
    const float* __restrict__ x, const float* __restrict__ gamma,
    const float* __restrict__ beta, float* __restrict__ out) {
  __shared__ float s_sum[8][32];
  __shared__ float s_sq[8][32];
  int t = threadIdx.x;
  int nl = t & 31, cg = t >> 5;
  int p0 = blockIdx.x * 32;  // global position base (b*1024 + n0)
  int b = p0 >> 10;
  int n = (p0 & 1023) + nl;
  const float* xp = x + ((size_t)b * 256 + cg * 32) * 1024 + n;
  float v[32];
  float sum = 0.f, sq = 0.f;
#pragma unroll
  for (int i = 0; i < 32; ++i) {
    float val = xp[(size_t)i * 1024];
    v[i] = val;
    sum += val;
    sq += val * val;
  }
  s_sum[cg][nl] = sum;
  s_sq[cg][nl] = sq;
  __syncthreads();
  float ts = 0.f, tq = 0.f;
#pragma unroll
  for (int g = 0; g < 8; ++g) {
    ts += s_sum[g][nl];
    tq += s_sq[g][nl];
  }
  float mu = ts * (1.f / 256.f);
  float var = tq * (1.f / 256.f) - mu * mu;
  float rs = rsqrtf(var + EPSF);
  float* op = out + ((size_t)b * 256 + cg * 32) * 1024 + n;
#pragma unroll
  for (int i = 0; i < 32; ++i) {
    int c = cg * 32 + i;
    op[(size_t)i * 1024] = (v[i] - mu) * rs * gamma[c] + beta[c];
  }
}

// ---------------------------------------------------------------------------
// MFMA GEMM: out[b,o,n] = epilogue( sum_c W[o,c] * X[b,c,n] ).
// Block 256 thr = 4 waves (2x2), tile 64o x 64n, BK=32, bf16 MFMA 16x16x32.
// X (f32 [b][c][n]) is transposed+converted to bf16 during LDS staging.
// LDS rows padded to 40 bf16 (80B): 16B frag reads land on distinct banks.
// ---------------------------------------------------------------------------
__global__ __launch_bounds__(256) void mfma_gemm_kernel(
    const float* __restrict__ X,     // [B, K, 1024]
    const float* __restrict__ W,     // [OC, K]
    const float* __restrict__ bn,    // [4, OC] or null
    const float* __restrict__ bias,  // [OC] or null
    const float* __restrict__ add1,  // [B, OC, 1024] or null
    const float* __restrict__ add2,  // [B, OC, 1024] or null
    float* __restrict__ out,         // [B, OC, 1024]
    int OC, int K, int OT) {
  __shared__ __hip_bfloat16 Wl[64][40];
  __shared__ __hip_bfloat16 Xl[64][40];
  int bx = blockIdx.x;
  int ot = bx % OT;
  int ntb = bx / OT;
  int b = ntb >> 4;
  int n0 = (ntb & 15) * 64;
  int o0 = ot * 64;
  int t = threadIdx.x;
  int lane = t & 63, w = t >> 6;
  int wo = w >> 1, wn = w & 1;
  f32x4 acc[2][2] = {};
  const float* Xb = X + (size_t)b * K * 1024 + n0;
  int nsteps = (K + 31) >> 5;
  // staging index precompute
  int so = t >> 2, sc8 = (t & 3) * 8;  // W: row so (64), 8 cols each
  int sn = t & 63, scl = t >> 6;       // X: col n = sn, rows scl + 4*p
  int g = lane >> 4;
  int r = lane & 15;
  for (int ks = 0; ks < nsteps; ++ks) {
    int k0 = ks << 5;
    __syncthreads();
    // stage W tile [64][32]
    {
      bool orow = (o0 + so) < OC;
      const float* wr = W + (size_t)(o0 + so) * K + k0 + sc8;
#pragma unroll
      for (int e = 0; e < 8; ++e) {
        float v = (orow && (k0 + sc8 + e) < K) ? wr[e] : 0.f;
        Wl[so][sc8 + e] = __float2bfloat16(v);
      }
    }
    // stage X tile transposed [64 n][32 c]
#pragma unroll
    for (int p = 0; p < 8; ++p) {
      int c = p * 4 + scl;
      float v = (k0 + c) < K ? Xb[(size_t)(k0 + c) * 1024 + sn] : 0.f;
      Xl[sn][c] = __float2bfloat16(v);
    }
    __syncthreads();
    short8 a0 = *reinterpret_cast<const short8*>(&Wl[wo * 32 + r][g * 8]);
    short8 a1 = *reinterpret_cast<const short8*>(&Wl[wo * 32 + 16 + r][g * 8]);
    short8 b0 = *reinterpret_cast<const short8*>(&Xl[wn * 32 + r][g * 8]);
    short8 b1 = *reinterpret_cast<const short8*>(&Xl[wn * 32 + 16 + r][g * 8]);
    acc[0][0] = __builtin_amdgcn_mfma_f32_16x16x32_bf16(a0, b0, acc[0][0], 0, 0, 0);
    acc[0][1] = __builtin_amdgcn_mfma_f32_16x16x32_bf16(a0, b1, acc[0][1], 0, 0, 0);
    acc[1][0] = __builtin_amdgcn_mfma_f32_16x16x32_bf16(a1, b0, acc[1][0], 0, 0, 0);
    acc[1][1] = __builtin_amdgcn_mfma_f32_16x16x32_bf16(a1, b1, acc[1][1], 0, 0, 0);
  }
  // epilogue: frag (i,j), reg rr -> o = o0+wo*32+i*16+g*4+rr, n = n0+wn*32+j*16+r
#pragma unroll
  for (int i = 0; i < 2; ++i) {
#pragma unroll
    for (int j = 0; j < 2; ++j) {
#pragma unroll
      for (int rr = 0; rr < 4; ++rr) {
        int o = o0 + wo * 32 + i * 16 + g * 4 + rr;
        if (o >= OC) continue;
        int n = n0 + wn * 32 + j * 16 + r;
        float v = acc[i][j][rr];
        if (bn) {
          float gg = bn[o], bb = bn[OC + o], m = bn[2 * OC + o],
                vv = bn[3 * OC + o];
          v = (v - m) * (gg * rsqrtf(vv + EPSF)) + bb;
        }
        if (bias) v += bias[o];
        size_t idx = ((size_t)b * OC + o) * 1024 + n;
        if (add1) v += add1[idx];
        if (add2) v += add2[idx];
        out[idx] = v;
      }
    }
  }
}

// ---------------------------------------------------------------------------
// Attention, split-m flash: block = 64 queries x 4 m-chunks (256 m each).
// grid = B*NH*16 = 1024 blocks. Per-thread two-pass over its 256-m chunk
// (K/V via wave-uniform global float4 loads, L1/L2-resident), then LDS
// combine of {max, scaled sum, acc[32]} across the 4 chunks.
// ---------------------------------------------------------------------------
__global__ __launch_bounds__(256) void attn_kernel(
    const float* __restrict__ qkv, float* __restrict__ o) {
  __shared__ float s_acc[256][33];
  __shared__ float s_mx[256];
  __shared__ float s_sf[256];
  __shared__ float s_se[256];
  int blk = blockIdx.x;
  int qt = blk & 15;
  int h = (blk >> 4) & 7;
  int b = blk >> 7;
  const float* base = qkv + ((size_t)b * 512 + h * 64) * 1024;
  int t = threadIdx.x;
  int ql = t & 63, ch = t >> 6;
  int n = qt * 64 + ql;
  float q[16];
#pragma unroll
  for (int k = 0; k < 16; ++k) q[k] = base[(size_t)k * 1024 + n] * 0.25f;
  const float* Kp = base + 16 * 1024 + ch * 256;
  const float* Vp = base + 32 * 1024 + ch * 256;
  // pass 1: chunk max
  float mx = -1e30f;
  for (int m4 = 0; m4 < 64; ++m4) {
    float s0 = 0.f, s1 = 0.f, s2 = 0.f, s3 = 0.f;
#pragma unroll
    for (int k = 0; k < 16; ++k) {
      const float4 kv = *reinterpret_cast<const float4*>(&Kp[(size_t)k * 1024 + m4 * 4]);
      s0 += q[k] * kv.x;
      s1 += q[k] * kv.y;
      s2 += q[k] * kv.z;
      s3 += q[k] * kv.w;
    }
    mx = fmaxf(mx, fmaxf(fmaxf(s0, s1), fmaxf(s2, s3)));
  }
  // pass 2: exp-sum + PV over chunk
  float acc[32] = {};
  float se = 0.f;
  for (int m4 = 0; m4 < 64; ++m4) {
    float s0 = 0.f, s1 = 0.f, s2 = 0.f, s3 = 0.f;
#pragma unroll
    for (int k = 0; k < 16; ++k) {
      const float4 kv = *reinterpret_cast<const float4*>(&Kp[(size_t)k * 1024 + m4 * 4]);
      s0 += q[k] * kv.x;
      s1 += q[k] * kv.y;
      s2 += q[k] * kv.z;
      s3 += q[k] * kv.w;
    }
    float p0 = __expf(s0 - mx), p1 = __expf(s1 - mx);
    float p2 = __expf(s2 - mx), p3 = __expf(s3 - mx);
    se += (p0 + p1) + (p2 + p3);
#pragma unroll
    for (int d = 0; d < 32; ++d) {
      const float4 vv = *reinterpret_cast<const float4*>(&Vp[(size_t)d * 1024 + m4 * 4]);
      acc[d] += p0 * vv.x + p1 * vv.y + p2 * vv.z + p3 * vv.w;
    }
  }
  // combine across 4 chunks
  s_mx[t] = mx;
  __syncthreads();
  float gm = fmaxf(fmaxf(s_mx[ql], s_mx[64 + ql]),
                   fmaxf(s_mx[128 + ql], s_mx[192 + ql]));
  float f = __expf(mx - gm);
  s_sf[t] = f;
  s_se[t] = se * f;
#pragma unroll
  for (int d = 0; d < 32; ++d) s_acc[t][d] = acc[d];
  __syncthreads();
  int qq = t & 63, d0 = (t >> 6) * 8;
  float setot = s_se[qq] + s_se[64 + qq] + s_se[128 + qq] + s_se[192 + qq];
  float inv = 1.f / setot;
  float* op = o + ((size_t)b * 256 + h * 32) * 1024 + qt * 64 + qq;
#pragma unroll
  for (int dd = 0; dd < 8; ++dd) {
    int d = d0 + dd;
    float v = s_acc[qq][d] * s_sf[qq] + s_acc[64 + qq][d] * s_sf[64 + qq] +
              s_acc[128 + qq][d] * s_sf[128 + qq] +
              s_acc[192 + qq][d] * s_sf[192 + qq];
    op[(size_t)d * 1024] = v * inv;
  }
}

// ---------------------------------------------------------------------------
// PE: o += bn(dwconv3x3(v_img, pe_w), pe_bn). v_img channel c -> qkv row
// (c/32)*64 + 32 + (c%32). One thread per output element.
// ---------------------------------------------------------------------------
__global__ __launch_bounds__(256) void pe_kernel(
    const float* __restrict__ qkv, const float* __restrict__ pe_w,
    const float* __restrict__ pe_bn, float* __restrict__ o) {
  int idx = blockIdx.x * 256 + threadIdx.x;  // [0, B*256*1024)
  int n = idx & 1023;
  int c = (idx >> 10) & 255;
  int b = idx >> 18;
  int y = n >> 5, xx = n & 31;
  int head = c >> 5, d = c & 31;
  const float* v = qkv + ((size_t)b * 512 + head * 64 + 32 + d) * 1024;
  const float* wp = pe_w + c * 9;
  float s = 0.f;
#pragma unroll
  for (int dy = -1; dy <= 1; ++dy) {
    int yy = y + dy;
    if (yy < 0 || yy > 31) continue;
#pragma unroll
    for (int dx = -1; dx <= 1; ++dx) {
      int xw = xx + dx;
      if (xw < 0 || xw > 31) continue;
      s += wp[(dy + 1) * 3 + (dx + 1)] * v[yy * 32 + xw];
    }
  }
  float g = pe_bn[c], bb = pe_bn[256 + c], m = pe_bn[512 + c],
        var = pe_bn[768 + c];
  s = (s - m) * (g * rsqrtf(var + EPSF)) + bb;
  o[idx] += s;
}

// ---------------------------------------------------------------------------
// CGLU inner: act = gelu_exact(dwconv3x3(a, dw_w) + dw_b) * g.
// ---------------------------------------------------------------------------
__global__ __launch_bounds__(256) void glu_kernel(
    const float* __restrict__ h, const float* __restrict__ dw_w,
    const float* __restrict__ dw_b, float* __restrict__ act) {
  int idx = blockIdx.x * 256 + threadIdx.x;
  if (idx >= 8 * 170 * 1024) return;
  int n = idx & 1023;
  int cn = idx >> 10;
  int cc = cn % 170;
  int b = cn / 170;
  int y = n >> 5, xx = n & 31;
  const float* a = h + ((size_t)b * 340 + cc) * 1024;
  const float* g = h + ((size_t)b * 340 + 170 + cc) * 1024;
  const float* wp = dw_w + cc * 9;
  float s = dw_b[cc];
#pragma unroll
  for (int dy = -1; dy <= 1; ++dy) {
    int yy = y + dy;
    if (yy < 0 || yy > 31) continue;
#pragma unroll
    for (int dx = -1; dx <= 1; ++dx) {
      int xw = xx + dx;
      if (xw < 0 || xw > 31) continue;
      s += wp[(dy + 1) * 3 + (dx + 1)] * a[yy * 32 + xw];
    }
  }
  float ge = 0.5f * s * (1.f + erff(s * 0.70710678118654752f));
  act[idx] = ge * g[n];
}

// ---------------------------------------------------------------------------
extern "C" void kernel_launch(void* const* d_in, const int* in_sizes, int n_in,
                              void* d_out, int out_size, void* d_ws,
                              size_t ws_size, hipStream_t stream) {
  const float* x      = (const float*)d_in[0];
  const float* ln1_g  = (const float*)d_in[1];
  const float* ln1_b  = (const float*)d_in[2];
  const float* ln2_g  = (const float*)d_in[3];
  const float* ln2_b  = (const float*)d_in[4];
  const float* qkv_w  = (const float*)d_in[5];
  const float* qkv_bn = (const float*)d_in[6];
  const float* pe_w   = (const float*)d_in[7];
  const float* pe_bn  = (const float*)d_in[8];
  const float* proj_w = (const float*)d_in[9];
  const float* proj_bn= (const float*)d_in[10];
  const float* fc1_w  = (const float*)d_in[11];
  const float* fc1_b  = (const float*)d_in[12];
  const float* dw_w   = (const float*)d_in[13];
  const float* dw_b   = (const float*)d_in[14];
  const float* fc2_w  = (const float*)d_in[15];
  const float* fc2_b  = (const float*)d_in[16];

  float* ws = (float*)d_ws;
  const size_t M = 1024 * 1024;
  float* xn   = ws;           // [B,256,1024]
  float* qkvb = ws + 2 * M;   // [B,512,1024]
  float* ob   = ws + 6 * M;   // [B,256,1024]
  float* x1   = ws + 8 * M;   // [B,256,1024]
  float* xn2  = ws + 10 * M;  // [B,256,1024]
  float* hb   = qkvb;         // fc1 out [B,340,1024]
  float* act  = xn;           // [B,170,1024]
  float* outp = (float*)d_out;

  // 1. xn = LN1(x)
  hipLaunchKernelGGL(ln_kernel, dim3(256), dim3(256), 0, stream, x, ln1_g,
                     ln1_b, xn);
  // 2. qkv = BN(qkv_w @ xn)   [B,512,1024]
  hipLaunchKernelGGL(mfma_gemm_kernel, dim3(8 * 128), dim3(256), 0, stream,
                     xn, qkv_w, qkv_bn, nullptr, nullptr, nullptr, qkvb, 512,
                     256, 8);
  // 3. ob = attention(qkv)    [B,256,1024]
  hipLaunchKernelGGL(attn_kernel, dim3(1024), dim3(256), 0, stream, qkvb, ob);
  // 4. ob += BN(dwconv3x3(v))
  hipLaunchKernelGGL(pe_kernel, dim3(8192), dim3(256), 0, stream, qkvb, pe_w,
                     pe_bn, ob);
  // 5. x1 = x + BN(proj_w @ ob)
  hipLaunchKernelGGL(mfma_gemm_kernel, dim3(4 * 128), dim3(256), 0, stream,
                     ob, proj_w, proj_bn, nullptr, x, nullptr, x1, 256, 256,
                     4);
  // 6. xn2 = LN2(x1)
  hipLaunchKernelGGL(ln_kernel, dim3(256), dim3(256), 0, stream, x1, ln2_g,
                     ln2_b, xn2);
  // 7. hb = fc1_w @ xn2 + fc1_b    [B,340,1024]
  hipLaunchKernelGGL(mfma_gemm_kernel, dim3(6 * 128), dim3(256), 0, stream,
                     xn2, fc1_w, nullptr, fc1_b, nullptr, nullptr, hb, 340,
                     256, 6);
  // 8. act = gelu(dwconv(a)+dw_b) * g
  hipLaunchKernelGGL(glu_kernel, dim3(5440), dim3(256), 0, stream, hb, dw_w,
                     dw_b, act);
  // 9. out = x1 + xn2 + fc2_w @ act + fc2_b
  hipLaunchKernelGGL(mfma_gemm_kernel, dim3(4 * 128), dim3(256), 0, stream,
                     act, fc2_w, nullptr, fc2_b, x1, xn2, outp, 256, 170, 4);
}

// Round 3
// 289.585 us; speedup vs baseline: 3.3085x; 2.8556x over previous
//
#include <hip/hip_runtime.h>
#include <hip/hip_bf16.h>
#include <math.h>

#define EPSF 1e-5f

using short4v = __attribute__((ext_vector_type(4))) short;
using short8 = __attribute__((ext_vector_type(8))) short;
using f32x4 = __attribute__((ext_vector_type(4))) float;

__device__ inline short bfbits(float x) {
  __hip_bfloat16 h = __float2bfloat16(x);
  return __builtin_bit_cast(short, h);
}

// ---------------------------------------------------------------------------
// LN over channel dim (C=256) of [B,256,32,32].
// ---------------------------------------------------------------------------
__global__ __launch_bounds__(256) void ln_kernel(
    const float* __restrict__ x, const float* __restrict__ gamma,
    const float* __restrict__ beta, float* __restrict__ out) {
  __shared__ float s_sum[8][32];
  __shared__ float s_sq[8][32];
  int t = threadIdx.x;
  int nl = t & 31, cg = t >> 5;
  int p0 = blockIdx.x * 32;
  int b = p0 >> 10;
  int n = (p0 & 1023) + nl;
  const float* xp = x + ((size_t)b * 256 + cg * 32) * 1024 + n;
  float v[32];
  float sum = 0.f, sq = 0.f;
#pragma unroll
  for (int i = 0; i < 32; ++i) {
    float val = xp[(size_t)i * 1024];
    v[i] = val;
    sum += val;
    sq += val * val;
  }
  s_sum[cg][nl] = sum;
  s_sq[cg][nl] = sq;
  __syncthreads();
  float ts = 0.f, tq = 0.f;
#pragma unroll
  for (int g = 0; g < 8; ++g) {
    ts += s_sum[g][nl];
    tq += s_sq[g][nl];
  }
  float mu = ts * (1.f / 256.f);
  float var = tq * (1.f / 256.f) - mu * mu;
  float rs = rsqrtf(var + EPSF);
  float* op = out + ((size_t)b * 256 + cg * 32) * 1024 + n;
#pragma unroll
  for (int i = 0; i < 32; ++i) {
    int c = cg * 32 + i;
    op[(size_t)i * 1024] = (v[i] - mu) * rs * gamma[c] + beta[c];
  }
}

// ---------------------------------------------------------------------------
// MFMA GEMM: out[b,o,n] = epilogue( sum_c W[o,c] * X[b,c,n] ).
// Block 256 thr = 4 waves (2x2), tile 64o x 64n, BK=32, bf16 MFMA 16x16x32.
// ---------------------------------------------------------------------------
__global__ __launch_bounds__(256) void mfma_gemm_kernel(
    const float* __restrict__ X, const float* __restrict__ W,
    const float* __restrict__ bn, const float* __restrict__ bias,
    const float* __restrict__ add1, const float* __restrict__ add2,
    float* __restrict__ out, int OC, int K, int OT) {
  __shared__ __hip_bfloat16 Wl[64][40];
  __shared__ __hip_bfloat16 Xl[64][40];
  int bx = blockIdx.x;
  int ot = bx % OT;
  int ntb = bx / OT;
  int b = ntb >> 4;
  int n0 = (ntb & 15) * 64;
  int o0 = ot * 64;
  int t = threadIdx.x;
  int lane = t & 63, w = t >> 6;
  int wo = w >> 1, wn = w & 1;
  f32x4 acc[2][2] = {};
  const float* Xb = X + (size_t)b * K * 1024 + n0;
  int nsteps = (K + 31) >> 5;
  int so = t >> 2, sc8 = (t & 3) * 8;
  int sn = t & 63, scl = t >> 6;
  int g = lane >> 4;
  int r = lane & 15;
  bool k4ok = (K & 3) == 0;
  for (int ks = 0; ks < nsteps; ++ks) {
    int k0 = ks << 5;
    __syncthreads();
    // stage W tile [64][32] (vectorized when safe)
    {
      bool orow = (o0 + so) < OC;
      const float* wr = W + (size_t)(o0 + so) * K + k0 + sc8;
      float v[8];
      if (orow && k4ok && (k0 + sc8 + 8 <= K)) {
        float4 w0 = *reinterpret_cast<const float4*>(wr);
        float4 w1 = *reinterpret_cast<const float4*>(wr + 4);
        v[0] = w0.x; v[1] = w0.y; v[2] = w0.z; v[3] = w0.w;
        v[4] = w1.x; v[5] = w1.y; v[6] = w1.z; v[7] = w1.w;
      } else {
#pragma unroll
        for (int e = 0; e < 8; ++e)
          v[e] = (orow && (k0 + sc8 + e) < K) ? wr[e] : 0.f;
      }
#pragma unroll
      for (int e = 0; e < 8; ++e) Wl[so][sc8 + e] = __float2bfloat16(v[e]);
    }
    // stage X tile transposed [64 n][32 c]
#pragma unroll
    for (int p = 0; p < 8; ++p) {
      int c = p * 4 + scl;
      float v = (k0 + c) < K ? Xb[(size_t)(k0 + c) * 1024 + sn] : 0.f;
      Xl[sn][c] = __float2bfloat16(v);
    }
    __syncthreads();
    short8 a0 = *reinterpret_cast<const short8*>(&Wl[wo * 32 + r][g * 8]);
    short8 a1 = *reinterpret_cast<const short8*>(&Wl[wo * 32 + 16 + r][g * 8]);
    short8 b0 = *reinterpret_cast<const short8*>(&Xl[wn * 32 + r][g * 8]);
    short8 b1 = *reinterpret_cast<const short8*>(&Xl[wn * 32 + 16 + r][g * 8]);
    acc[0][0] = __builtin_amdgcn_mfma_f32_16x16x32_bf16(a0, b0, acc[0][0], 0, 0, 0);
    acc[0][1] = __builtin_amdgcn_mfma_f32_16x16x32_bf16(a0, b1, acc[0][1], 0, 0, 0);
    acc[1][0] = __builtin_amdgcn_mfma_f32_16x16x32_bf16(a1, b0, acc[1][0], 0, 0, 0);
    acc[1][1] = __builtin_amdgcn_mfma_f32_16x16x32_bf16(a1, b1, acc[1][1], 0, 0, 0);
  }
#pragma unroll
  for (int i = 0; i < 2; ++i) {
#pragma unroll
    for (int j = 0; j < 2; ++j) {
#pragma unroll
      for (int rr = 0; rr < 4; ++rr) {
        int o = o0 + wo * 32 + i * 16 + g * 4 + rr;
        if (o >= OC) continue;
        int n = n0 + wn * 32 + j * 16 + r;
        float v = acc[i][j][rr];
        if (bn) {
          float gg = bn[o], bb = bn[OC + o], m = bn[2 * OC + o],
                vv = bn[3 * OC + o];
          v = (v - m) * (gg * rsqrtf(vv + EPSF)) + bb;
        }
        if (bias) v += bias[o];
        size_t idx = ((size_t)b * OC + o) * 1024 + n;
        if (add1) v += add1[idx];
        if (add2) v += add2[idx];
        out[idx] = v;
      }
    }
  }
}

// ---------------------------------------------------------------------------
// MFMA flash attention. Block = 256 thr (4 waves x 16 queries), one (b,h),
// 64-query tile. Loop over 16 m-chunks of 64: stage K,V (bf16) in LDS,
// S^T = K·Q via mfma (kd zero-padded 16->32), online softmax in-register
// (lane holds 16 m-values of one query column), P fed back as PV A-frag.
// grid = B*NH*16 = 1024 blocks.
// ---------------------------------------------------------------------------
__global__ __launch_bounds__(256) void attn_mfma_kernel(
    const float* __restrict__ qkv, float* __restrict__ o) {
  __shared__ __hip_bfloat16 Ql[64][40];
  __shared__ __hip_bfloat16 Kl[64][40];
  __shared__ __hip_bfloat16 Vl[32][72];
  int blk = blockIdx.x;
  int qt = blk & 15, h = (blk >> 4) & 7, b = blk >> 7;
  const float* Qg = qkv + ((size_t)b * 512 + h * 64) * 1024;
  const float* Kg = Qg + 16 * 1024;
  const float* Vg = Qg + 32 * 1024;
  int t = threadIdx.x;
  int lane = t & 63, w = t >> 6;
  int g = lane >> 4, r = lane & 15;
  int q0 = qt * 64;
  // zero the padded kd cols (16..31) of Ql, Kl once
  for (int i = t; i < 64 * 16; i += 256) {
    int row = i >> 4, col = 16 + (i & 15);
    Ql[row][col] = __float2bfloat16(0.f);
    Kl[row][col] = __float2bfloat16(0.f);
  }
  // stage Q tile (scaled by KD^-0.5 = 0.25), transposed to [q][kd]
  {
    int kd = t & 15, q4 = t >> 4;
    float4 qv =
        *reinterpret_cast<const float4*>(&Qg[(size_t)kd * 1024 + q0 + q4 * 4]);
    Ql[q4 * 4 + 0][kd] = __float2bfloat16(qv.x * 0.25f);
    Ql[q4 * 4 + 1][kd] = __float2bfloat16(qv.y * 0.25f);
    Ql[q4 * 4 + 2][kd] = __float2bfloat16(qv.z * 0.25f);
    Ql[q4 * 4 + 3][kd] = __float2bfloat16(qv.w * 0.25f);
  }
  __syncthreads();
  // per-wave Q fragment (B operand), constant across chunks
  short8 qf = *reinterpret_cast<const short8*>(&Ql[w * 16 + r][g * 8]);
  float M = -3e38f, l = 0.f;
  f32x4 O0 = {}, O1 = {};
  int skd = t & 15, smq = t >> 4;    // K staging indices
  int sd = t >> 3, smq2 = t & 7;     // V staging indices
  for (int ch = 0; ch < 16; ++ch) {
    int m0 = ch * 64;
    // stage K chunk transposed -> Kl[m][kd]
    {
      float4 kv = *reinterpret_cast<const float4*>(
          &Kg[(size_t)skd * 1024 + m0 + smq * 4]);
      Kl[smq * 4 + 0][skd] = __float2bfloat16(kv.x);
      Kl[smq * 4 + 1][skd] = __float2bfloat16(kv.y);
      Kl[smq * 4 + 2][skd] = __float2bfloat16(kv.z);
      Kl[smq * 4 + 3][skd] = __float2bfloat16(kv.w);
    }
    // stage V chunk -> Vl[d][m]
#pragma unroll
    for (int h2 = 0; h2 < 2; ++h2) {
      int mq = smq2 + 8 * h2;
      float4 vv = *reinterpret_cast<const float4*>(
          &Vg[(size_t)sd * 1024 + m0 + mq * 4]);
      short4v vs = {bfbits(vv.x), bfbits(vv.y), bfbits(vv.z), bfbits(vv.w)};
      *reinterpret_cast<short4v*>(&Vl[sd][mq * 4]) = vs;
    }
    __syncthreads();
    // S^T tiles: D[m][q], m-tile mt. lane holds S[m=mt*16+g*4+reg][q=w*16+r]
    f32x4 s[4];
#pragma unroll
    for (int mt = 0; mt < 4; ++mt) {
      short8 af = *reinterpret_cast<const short8*>(&Kl[mt * 16 + r][g * 8]);
      f32x4 z = {};
      s[mt] = __builtin_amdgcn_mfma_f32_16x16x32_bf16(af, qf, z, 0, 0, 0);
    }
    // chunk max over 64 m (16 in-lane + across g-groups)
    float mx = -3e38f;
#pragma unroll
    for (int mt = 0; mt < 4; ++mt)
      mx = fmaxf(mx, fmaxf(fmaxf(s[mt][0], s[mt][1]), fmaxf(s[mt][2], s[mt][3])));
    mx = fmaxf(mx, __shfl_xor(mx, 16));
    mx = fmaxf(mx, __shfl_xor(mx, 32));
    float Mn = fmaxf(M, mx);
    float f = __expf(M - Mn);
    M = Mn;
    // P = exp(S - Mn), chunk sum, pack as PV A-fragments (regs 4..7 = 0)
    float sc = 0.f;
    short8 pa[4];
#pragma unroll
    for (int mt = 0; mt < 4; ++mt) {
      float p0 = __expf(s[mt][0] - Mn);
      float p1 = __expf(s[mt][1] - Mn);
      float p2 = __expf(s[mt][2] - Mn);
      float p3 = __expf(s[mt][3] - Mn);
      sc += (p0 + p1) + (p2 + p3);
      pa[mt] = (short8){bfbits(p0), bfbits(p1), bfbits(p2), bfbits(p3),
                        0, 0, 0, 0};
    }
    sc += __shfl_xor(sc, 16);
    sc += __shfl_xor(sc, 32);
    l = l * f + sc;
    // rescale O accumulators; O rows are q = g*4+reg -> fetch f per row
#pragma unroll
    for (int rr = 0; rr < 4; ++rr) {
      float fr = __shfl(f, g * 4 + rr);
      O0[rr] *= fr;
      O1[rr] *= fr;
    }
    // PV: O[q][d] += P[q][m16] * V^T[m16][d], zero-padded K=16 per mfma
#pragma unroll
    for (int mt = 0; mt < 4; ++mt) {
      short4v v0 = *reinterpret_cast<const short4v*>(&Vl[r][mt * 16 + g * 4]);
      short4v v1 =
          *reinterpret_cast<const short4v*>(&Vl[16 + r][mt * 16 + g * 4]);
      short8 b0 = {v0[0], v0[1], v0[2], v0[3], 0, 0, 0, 0};
      short8 b1 = {v1[0], v1[1], v1[2], v1[3], 0, 0, 0, 0};
      O0 = __builtin_amdgcn_mfma_f32_16x16x32_bf16(pa[mt], b0, O0, 0, 0, 0);
      O1 = __builtin_amdgcn_mfma_f32_16x16x32_bf16(pa[mt], b1, O1, 0, 0, 0);
    }
    __syncthreads();
  }
  // normalize and write: O[q = w*16+g*4+rr][d = dt*16+r]
  float* ob = o + ((size_t)b * 256 + h * 32) * 1024 + q0 + w * 16;
#pragma unroll
  for (int rr = 0; rr < 4; ++rr) {
    float lr = __shfl(l, g * 4 + rr);
    float inv = 1.f / lr;
    int q = g * 4 + rr;
    ob[(size_t)r * 1024 + q] = O0[rr] * inv;
    ob[(size_t)(16 + r) * 1024 + q] = O1[rr] * inv;
  }
}

// ---------------------------------------------------------------------------
// PE: o += bn(dwconv3x3(v_img, pe_w), pe_bn).
// ---------------------------------------------------------------------------
__global__ __launch_bounds__(256) void pe_kernel(
    const float* __restrict__ qkv, const float* __restrict__ pe_w,
    const float* __restrict__ pe_bn, float* __restrict__ o) {
  int idx = blockIdx.x * 256 + threadIdx.x;
  int n = idx & 1023;
  int c = (idx >> 10) & 255;
  int b = idx >> 18;
  int y = n >> 5, xx = n & 31;
  int head = c >> 5, d = c & 31;
  const float* v = qkv + ((size_t)b * 512 + head * 64 + 32 + d) * 1024;
  const float* wp = pe_w + c * 9;
  float s = 0.f;
#pragma unroll
  for (int dy = -1; dy <= 1; ++dy) {
    int yy = y + dy;
    if (yy < 0 || yy > 31) continue;
#pragma unroll
    for (int dx = -1; dx <= 1; ++dx) {
      int xw = xx + dx;
      if (xw < 0 || xw > 31) continue;
      s += wp[(dy + 1) * 3 + (dx + 1)] * v[yy * 32 + xw];
    }
  }
  float g = pe_bn[c], bb = pe_bn[256 + c], m = pe_bn[512 + c],
        var = pe_bn[768 + c];
  s = (s - m) * (g * rsqrtf(var + EPSF)) + bb;
  o[idx] += s;
}

// ---------------------------------------------------------------------------
// CGLU inner: act = gelu_exact(dwconv3x3(a, dw_w) + dw_b) * g.
// ---------------------------------------------------------------------------
__global__ __launch_bounds__(256) void glu_kernel(
    const float* __restrict__ h, const float* __restrict__ dw_w,
    const float* __restrict__ dw_b, float* __restrict__ act) {
  int idx = blockIdx.x * 256 + threadIdx.x;
  if (idx >= 8 * 170 * 1024) return;
  int n = idx & 1023;
  int cn = idx >> 10;
  int cc = cn % 170;
  int b = cn / 170;
  int y = n >> 5, xx = n & 31;
  const float* a = h + ((size_t)b * 340 + cc) * 1024;
  const float* g = h + ((size_t)b * 340 + 170 + cc) * 1024;
  const float* wp = dw_w + cc * 9;
  float s = dw_b[cc];
#pragma unroll
  for (int dy = -1; dy <= 1; ++dy) {
    int yy = y + dy;
    if (yy < 0 || yy > 31) continue;
#pragma unroll
    for (int dx = -1; dx <= 1; ++dx) {
      int xw = xx + dx;
      if (xw < 0 || xw > 31) continue;
      s += wp[(dy + 1) * 3 + (dx + 1)] * a[yy * 32 + xw];
    }
  }
  float ge = 0.5f * s * (1.f + erff(s * 0.70710678118654752f));
  act[idx] = ge * g[n];
}

// ---------------------------------------------------------------------------
extern "C" void kernel_launch(void* const* d_in, const int* in_sizes, int n_in,
                              void* d_out, int out_size, void* d_ws,
                              size_t ws_size, hipStream_t stream) {
  const float* x      = (const float*)d_in[0];
  const float* ln1_g  = (const float*)d_in[1];
  const float* ln1_b  = (const float*)d_in[2];
  const float* ln2_g  = (const float*)d_in[3];
  const float* ln2_b  = (const float*)d_in[4];
  const float* qkv_w  = (const float*)d_in[5];
  const float* qkv_bn = (const float*)d_in[6];
  const float* pe_w   = (const float*)d_in[7];
  const float* pe_bn  = (const float*)d_in[8];
  const float* proj_w = (const float*)d_in[9];
  const float* proj_bn= (const float*)d_in[10];
  const float* fc1_w  = (const float*)d_in[11];
  const float* fc1_b  = (const float*)d_in[12];
  const float* dw_w   = (const float*)d_in[13];
  const float* dw_b   = (const float*)d_in[14];
  const float* fc2_w  = (const float*)d_in[15];
  const float* fc2_b  = (const float*)d_in[16];

  float* ws = (float*)d_ws;
  const size_t M = 1024 * 1024;
  float* xn   = ws;
  float* qkvb = ws + 2 * M;
  float* ob   = ws + 6 * M;
  float* x1   = ws + 8 * M;
  float* xn2  = ws + 10 * M;
  float* hb   = qkvb;
  float* act  = xn;
  float* outp = (float*)d_out;

  hipLaunchKernelGGL(ln_kernel, dim3(256), dim3(256), 0, stream, x, ln1_g,
                     ln1_b, xn);
  hipLaunchKernelGGL(mfma_gemm_kernel, dim3(8 * 128), dim3(256), 0, stream,
                     xn, qkv_w, qkv_bn, nullptr, nullptr, nullptr, qkvb, 512,
                     256, 8);
  hipLaunchKernelGGL(attn_mfma_kernel, dim3(1024), dim3(256), 0, stream, qkvb,
                     ob);
  hipLaunchKernelGGL(pe_kernel, dim3(8192), dim3(256), 0, stream, qkvb, pe_w,
                     pe_bn, ob);
  hipLaunchKernelGGL(mfma_gemm_kernel, dim3(4 * 128), dim3(256), 0, stream,
                     ob, proj_w, proj_bn, nullptr, x, nullptr, x1, 256, 256,
                     4);
  hipLaunchKernelGGL(ln_kernel, dim3(256), dim3(256), 0, stream, x1, ln2_g,
                     ln2_b, xn2);
  hipLaunchKernelGGL(mfma_gemm_kernel, dim3(6 * 128), dim3(256), 0, stream,
                     xn2, fc1_w, nullptr, fc1_b, nullptr, nullptr, hb, 340,
                     256, 6);
  hipLaunchKernelGGL(glu_kernel, dim3(5440), dim3(256), 0, stream, hb, dw_w,
                     dw_b, act);
  hipLaunchKernelGGL(mfma_gemm_kernel, dim3(4 * 128), dim3(256), 0, stream,
                     act, fc2_w, nullptr, fc2_b, x1, xn2, outp, 256, 170, 4);
}

// Round 4
// 205.893 us; speedup vs baseline: 4.6534x; 1.4065x over previous
//
#include <hip/hip_runtime.h>
#include <hip/hip_bf16.h>
#include <math.h>

#define EPSF 1e-5f

using short4v = __attribute__((ext_vector_type(4))) short;
using short8 = __attribute__((ext_vector_type(8))) short;
using f32x4 = __attribute__((ext_vector_type(4))) float;

__device__ inline short bfbits(float x) {
  __hip_bfloat16 h = __float2bfloat16(x);
  return __builtin_bit_cast(short, h);
}
__device__ inline float bf2f(short s) {
  unsigned u = ((unsigned)(unsigned short)s) << 16;
  return __builtin_bit_cast(float, u);
}

// ---------------------------------------------------------------------------
// prep: fold BN into weights/bias, convert weights to bf16 (padded), build
// pe tables. One flat-index kernel.
// segments: wq 512*256 | wpj 256*256 | wf1 384*256 | wf2 256*192 | pe 256*9
// ---------------------------------------------------------------------------
__global__ __launch_bounds__(256) void prep_kernel(
    const float* __restrict__ qkv_w, const float* __restrict__ qkv_bn,
    const float* __restrict__ proj_w, const float* __restrict__ proj_bn,
    const float* __restrict__ fc1_w, const float* __restrict__ fc2_w,
    const float* __restrict__ pe_w, const float* __restrict__ pe_bn,
    short* __restrict__ wq, float* __restrict__ bq, short* __restrict__ wpj,
    float* __restrict__ bpj, short* __restrict__ wf1, short* __restrict__ wf2,
    float* __restrict__ pw2, float* __restrict__ pb) {
  int id = blockIdx.x * 256 + threadIdx.x;
  if (id < 131072) {
    int o = id >> 8, k = id & 255;
    float g = qkv_bn[o], bb = qkv_bn[512 + o], m = qkv_bn[1024 + o],
          v = qkv_bn[1536 + o];
    float s = g * rsqrtf(v + EPSF);
    float s2 = ((o & 63) < 16) ? 0.25f : 1.0f;
    wq[id] = bfbits(qkv_w[id] * s * s2);
    if (k == 0) bq[o] = (bb - m * s) * s2;
  } else if (id < 196608) {
    int i = id - 131072;
    int o = i >> 8, k = i & 255;
    float g = proj_bn[o], bb = proj_bn[256 + o], m = proj_bn[512 + o],
          v = proj_bn[768 + o];
    float s = g * rsqrtf(v + EPSF);
    wpj[i] = bfbits(proj_w[i] * s);
    if (k == 0) bpj[o] = bb - m * s;
  } else if (id < 294912) {
    int i = id - 196608;
    int o = i >> 8, k = i & 255;
    wf1[i] = bfbits(o < 340 ? fc1_w[o * 256 + k] : 0.f);
  } else if (id < 344064) {
    int i = id - 294912;
    int o = i / 192, k = i - o * 192;
    wf2[i] = bfbits(k < 170 ? fc2_w[o * 170 + k] : 0.f);
  } else if (id < 346368) {
    int i = id - 344064;
    int c = i / 9;
    float g = pe_bn[c], bb = pe_bn[256 + c], m = pe_bn[512 + c],
          v = pe_bn[768 + c];
    float s = g * rsqrtf(v + EPSF);
    pw2[i] = pe_w[i] * s;
    if (i - c * 9 == 0) pb[c] = bb - m * s;
  }
}

// ---------------------------------------------------------------------------
// LN1: x f32 [b][c][n] -> xn bf16 channels-last [b][n][256].
// block 256 = 16 positions x 16 channel-groups(16ch). grid 512.
// ---------------------------------------------------------------------------
__global__ __launch_bounds__(256) void ln1_kernel(
    const float* __restrict__ x, const float* __restrict__ gamma,
    const float* __restrict__ beta, short* __restrict__ xn) {
  __shared__ float s_sum[16][16];
  __shared__ float s_sq[16][16];
  int t = threadIdx.x;
  int nl = t & 15, cg = t >> 4;
  int p0 = blockIdx.x * 16;
  int b = p0 >> 10;
  int n = (p0 & 1023) + nl;
  const float* xp = x + ((size_t)b * 256 + cg * 16) * 1024 + n;
  float v[16];
  float sum = 0.f, sq = 0.f;
#pragma unroll
  for (int i = 0; i < 16; ++i) {
    float val = xp[(size_t)i * 1024];
    v[i] = val;
    sum += val;
    sq += val * val;
  }
  s_sum[cg][nl] = sum;
  s_sq[cg][nl] = sq;
  __syncthreads();
  float ts = 0.f, tq = 0.f;
#pragma unroll
  for (int g = 0; g < 16; ++g) {
    ts += s_sum[g][nl];
    tq += s_sq[g][nl];
  }
  float mu = ts * (1.f / 256.f);
  float var = tq * (1.f / 256.f) - mu * mu;
  float rs = rsqrtf(var + EPSF);
  short8 pk[2];
#pragma unroll
  for (int i = 0; i < 16; ++i) {
    int c = cg * 16 + i;
    pk[i >> 3][i & 7] = bfbits((v[i] - mu) * rs * gamma[c] + beta[c]);
  }
  short* op = xn + ((size_t)b * 1024 + n) * 256 + cg * 16;
  *reinterpret_cast<short8*>(op) = pk[0];
  *reinterpret_cast<short8*>(op + 8) = pk[1];
}

// ---------------------------------------------------------------------------
// LN2: x1 f32 channels-last [pos][256] -> xn2 bf16 CL. block 256 = 4 waves,
// each wave 4 positions (lane = 4 channels). grid 512.
// ---------------------------------------------------------------------------
__global__ __launch_bounds__(256) void ln2_kernel(
    const float* __restrict__ x1, const float* __restrict__ gamma,
    const float* __restrict__ beta, short* __restrict__ xn2) {
  int t = threadIdx.x;
  int lane = t & 63, w = t >> 6;
  f32x4 gv = *reinterpret_cast<const f32x4*>(&gamma[lane * 4]);
  f32x4 bv = *reinterpret_cast<const f32x4*>(&beta[lane * 4]);
#pragma unroll
  for (int it = 0; it < 4; ++it) {
    size_t pos = blockIdx.x * 16 + w * 4 + it;
    f32x4 xv = *reinterpret_cast<const f32x4*>(&x1[pos * 256 + lane * 4]);
    float s = (xv[0] + xv[1]) + (xv[2] + xv[3]);
    float q = (xv[0] * xv[0] + xv[1] * xv[1]) + (xv[2] * xv[2] + xv[3] * xv[3]);
#pragma unroll
    for (int off = 1; off < 64; off <<= 1) {
      s += __shfl_xor(s, off);
      q += __shfl_xor(q, off);
    }
    float mu = s * (1.f / 256.f);
    float var = q * (1.f / 256.f) - mu * mu;
    float rs = rsqrtf(var + EPSF);
    short4v o;
#pragma unroll
    for (int e = 0; e < 4; ++e)
      o[e] = bfbits((xv[e] - mu) * rs * gv[e] + bv[e]);
    *reinterpret_cast<short4v*>(&xn2[pos * 256 + lane * 4]) = o;
  }
}

// ---------------------------------------------------------------------------
// MFMA GEMM v2: X bf16 CL [b][n][KS], W bf16 [OCpad][K]. Tile 64o x 64n,
// BK=32, 4 waves. MODE 0: out bf16 CL stride RS (+bias).
// MODE 1: out f32 CL 256 (+bias, + x channel-major).  (proj)
// MODE 2: out f32 channel-major d_out (+bias + x1 f32CL + xn2 bf16CL). (fc2)
// ---------------------------------------------------------------------------
template <int MODE>
__global__ __launch_bounds__(256) void gemm2_kernel(
    const short* __restrict__ X, const short* __restrict__ W,
    const float* __restrict__ bias, const float* __restrict__ addCM,
    const float* __restrict__ add1CL, const short* __restrict__ add2CL,
    void* __restrict__ out, int OC, int K, int OT, int KS, int RS) {
  __shared__ short Wl[64][40];
  __shared__ short Xl[64][40];
  int bx = blockIdx.x;
  int ot = bx % OT;
  int ntb = bx / OT;
  int b = ntb >> 4;
  int n0 = (ntb & 15) * 64;
  int o0 = ot * 64;
  int t = threadIdx.x;
  int lane = t & 63, w = t >> 6;
  int wo = w >> 1, wn = w & 1;
  int g = lane >> 4, r = lane & 15;
  int srow = t >> 2, sk8 = (t & 3) * 8;
  size_t bN = (size_t)b * 1024;
  f32x4 acc[2][2] = {};
  int nsteps = K >> 5;
  for (int ks = 0; ks < nsteps; ++ks) {
    int k0 = ks << 5;
    __syncthreads();
    short8 wv = *reinterpret_cast<const short8*>(&W[(size_t)(o0 + srow) * K + k0 + sk8]);
    short8 xv = *reinterpret_cast<const short8*>(&X[(bN + n0 + srow) * KS + k0 + sk8]);
    *reinterpret_cast<short8*>(&Wl[srow][sk8]) = wv;
    *reinterpret_cast<short8*>(&Xl[srow][sk8]) = xv;
    __syncthreads();
    short8 a0 = *reinterpret_cast<const short8*>(&Wl[wo * 32 + r][g * 8]);
    short8 a1 = *reinterpret_cast<const short8*>(&Wl[wo * 32 + 16 + r][g * 8]);
    short8 b0 = *reinterpret_cast<const short8*>(&Xl[wn * 32 + r][g * 8]);
    short8 b1 = *reinterpret_cast<const short8*>(&Xl[wn * 32 + 16 + r][g * 8]);
    acc[0][0] = __builtin_amdgcn_mfma_f32_16x16x32_bf16(a0, b0, acc[0][0], 0, 0, 0);
    acc[0][1] = __builtin_amdgcn_mfma_f32_16x16x32_bf16(a0, b1, acc[0][1], 0, 0, 0);
    acc[1][0] = __builtin_amdgcn_mfma_f32_16x16x32_bf16(a1, b0, acc[1][0], 0, 0, 0);
    acc[1][1] = __builtin_amdgcn_mfma_f32_16x16x32_bf16(a1, b1, acc[1][1], 0, 0, 0);
  }
#pragma unroll
  for (int i = 0; i < 2; ++i) {
#pragma unroll
    for (int j = 0; j < 2; ++j) {
      int oq = o0 + wo * 32 + i * 16 + g * 4;
      if (oq >= OC) continue;
      int n = n0 + wn * 32 + j * 16 + r;
      f32x4 bv = *reinterpret_cast<const f32x4*>(&bias[oq]);
      f32x4 res;
#pragma unroll
      for (int rr = 0; rr < 4; ++rr) res[rr] = acc[i][j][rr] + bv[rr];
      if constexpr (MODE == 0) {
        short4v s;
#pragma unroll
        for (int rr = 0; rr < 4; ++rr) s[rr] = bfbits(res[rr]);
        *reinterpret_cast<short4v*>((short*)out + (bN + n) * RS + oq) = s;
      } else if constexpr (MODE == 1) {
#pragma unroll
        for (int rr = 0; rr < 4; ++rr)
          res[rr] += addCM[((size_t)b * 256 + oq + rr) * 1024 + n];
        *reinterpret_cast<f32x4*>((float*)out + (bN + n) * 256 + oq) = res;
      } else {
        f32x4 a1v = *reinterpret_cast<const f32x4*>(&add1CL[(bN + n) * 256 + oq]);
        short4v a2v = *reinterpret_cast<const short4v*>(&add2CL[(bN + n) * 256 + oq]);
#pragma unroll
        for (int rr = 0; rr < 4; ++rr) {
          float v = res[rr] + a1v[rr] + bf2f(a2v[rr]);
          ((float*)out)[((size_t)b * 256 + oq + rr) * 1024 + n] = v;
        }
      }
    }
  }
}

// ---------------------------------------------------------------------------
// MFMA flash attention v2: qkv bf16 CL [b][n][512] (q pre-scaled).
// Block = 4 waves x 16 queries = 64-query tile of one (b,h). grid 1024.
// Writes ob f32 CL [b][n][256].
// ---------------------------------------------------------------------------
__global__ __launch_bounds__(256) void attn2_kernel(
    const short* __restrict__ qkv, float* __restrict__ ob) {
  __shared__ short Ql[64][40];
  __shared__ short Kl[64][40];
  __shared__ short Vl[32][72];
  int blk = blockIdx.x;
  int qt = blk & 15, h = (blk >> 4) & 7, b = blk >> 7;
  const short* base = qkv + (size_t)b * 1024 * 512 + h * 64;
  int t = threadIdx.x;
  int lane = t & 63, w = t >> 6;
  int g = lane >> 4, r = lane & 15;
  int q0 = qt * 64;
  for (int i = t; i < 64 * 16; i += 256) {
    int row = i >> 4, col = 16 + (i & 15);
    Ql[row][col] = 0;
    Kl[row][col] = 0;
  }
  {
    int qr = t >> 2, kd4 = (t & 3) * 4;
    short4v qv = *reinterpret_cast<const short4v*>(&base[(size_t)(q0 + qr) * 512 + kd4]);
    *reinterpret_cast<short4v*>(&Ql[qr][kd4]) = qv;
  }
  __syncthreads();
  short8 qf = *reinterpret_cast<const short8*>(&Ql[w * 16 + r][g * 8]);
  float M = -3e38f, l = 0.f;
  f32x4 O0 = {}, O1 = {};
  int mr4 = t >> 2, kd4 = (t & 3) * 4;
  int mrv = t & 63, dg = t >> 6;
  for (int ch = 0; ch < 16; ++ch) {
    int m0 = ch * 64;
    {
      short4v kv = *reinterpret_cast<const short4v*>(
          &base[(size_t)(m0 + mr4) * 512 + 16 + kd4]);
      *reinterpret_cast<short4v*>(&Kl[mr4][kd4]) = kv;
    }
    {
      short8 vv = *reinterpret_cast<const short8*>(
          &base[(size_t)(m0 + mrv) * 512 + 32 + dg * 8]);
#pragma unroll
      for (int e = 0; e < 8; ++e) Vl[dg * 8 + e][mrv] = vv[e];
    }
    __syncthreads();
    f32x4 s[4];
#pragma unroll
    for (int mt = 0; mt < 4; ++mt) {
      short8 af = *reinterpret_cast<const short8*>(&Kl[mt * 16 + r][g * 8]);
      f32x4 z = {};
      s[mt] = __builtin_amdgcn_mfma_f32_16x16x32_bf16(af, qf, z, 0, 0, 0);
    }
    float mx = -3e38f;
#pragma unroll
    for (int mt = 0; mt < 4; ++mt)
      mx = fmaxf(mx, fmaxf(fmaxf(s[mt][0], s[mt][1]), fmaxf(s[mt][2], s[mt][3])));
    mx = fmaxf(mx, __shfl_xor(mx, 16));
    mx = fmaxf(mx, __shfl_xor(mx, 32));
    float Mn = fmaxf(M, mx);
    float f = __expf(M - Mn);
    M = Mn;
    float sc = 0.f;
    short8 pa[4];
#pragma unroll
    for (int mt = 0; mt < 4; ++mt) {
      float p0 = __expf(s[mt][0] - Mn);
      float p1 = __expf(s[mt][1] - Mn);
      float p2 = __expf(s[mt][2] - Mn);
      float p3 = __expf(s[mt][3] - Mn);
      sc += (p0 + p1) + (p2 + p3);
      pa[mt] = (short8){bfbits(p0), bfbits(p1), bfbits(p2), bfbits(p3),
                        0, 0, 0, 0};
    }
    sc += __shfl_xor(sc, 16);
    sc += __shfl_xor(sc, 32);
    l = l * f + sc;
#pragma unroll
    for (int rr = 0; rr < 4; ++rr) {
      float fr = __shfl(f, g * 4 + rr);
      O0[rr] *= fr;
      O1[rr] *= fr;
    }
#pragma unroll
    for (int mt = 0; mt < 4; ++mt) {
      short4v v0 = *reinterpret_cast<const short4v*>(&Vl[r][mt * 16 + g * 4]);
      short4v v1 = *reinterpret_cast<const short4v*>(&Vl[16 + r][mt * 16 + g * 4]);
      short8 b0 = {v0[0], v0[1], v0[2], v0[3], 0, 0, 0, 0};
      short8 b1 = {v1[0], v1[1], v1[2], v1[3], 0, 0, 0, 0};
      O0 = __builtin_amdgcn_mfma_f32_16x16x32_bf16(pa[mt], b0, O0, 0, 0, 0);
      O1 = __builtin_amdgcn_mfma_f32_16x16x32_bf16(pa[mt], b1, O1, 0, 0, 0);
    }
    __syncthreads();
  }
  float* obp = ob + ((size_t)b * 1024 + q0 + w * 16) * 256 + h * 32;
#pragma unroll
  for (int rr = 0; rr < 4; ++rr) {
    float lr = __shfl(l, g * 4 + rr);
    float inv = 1.f / lr;
    size_t qoff = (size_t)(g * 4 + rr) * 256;
    obp[qoff + r] = O0[rr] * inv;
    obp[qoff + 16 + r] = O1[rr] * inv;
  }
}

// ---------------------------------------------------------------------------
// PE (channels-last): obf = bf16(ob + dwconv3x3(v)*s + pb). v = qkv CL cols
// head*64+32+d. grid 8192, c fastest.
// ---------------------------------------------------------------------------
__global__ __launch_bounds__(256) void pe2_kernel(
    const short* __restrict__ qkv, const float* __restrict__ pw2,
    const float* __restrict__ pb, const float* __restrict__ ob,
    short* __restrict__ obf) {
  int idx = blockIdx.x * 256 + threadIdx.x;
  int c = idx & 255;
  int n = (idx >> 8) & 1023;
  int b = idx >> 18;
  int y = n >> 5, xx = n & 31;
  int head = c >> 5, d = c & 31;
  const short* v = qkv + (size_t)b * 1024 * 512 + head * 64 + 32 + d;
  const float* wp = pw2 + c * 9;
  float s = pb[c];
#pragma unroll
  for (int dy = -1; dy <= 1; ++dy) {
    int yy = y + dy;
    if (yy < 0 || yy > 31) continue;
#pragma unroll
    for (int dx = -1; dx <= 1; ++dx) {
      int xw = xx + dx;
      if (xw < 0 || xw > 31) continue;
      s += wp[(dy + 1) * 3 + (dx + 1)] * bf2f(v[(size_t)(yy * 32 + xw) * 512]);
    }
  }
  obf[idx] = bfbits(ob[idx] + s);
}

// ---------------------------------------------------------------------------
// GLU (channels-last): act[n][192] = bf16(gelu(dwconv(a)+dw_b) * g), cols
// 170..191 zeroed. h bf16 [n][352]: a cols 0..169, g cols 170..339.
// block 192 thr, grid 8192 (one position each).
// ---------------------------------------------------------------------------
__global__ __launch_bounds__(192) void glu2_kernel(
    const short* __restrict__ h, const float* __restrict__ dw_w,
    const float* __restrict__ dw_b, short* __restrict__ act) {
  int n = blockIdx.x & 1023;
  int b = blockIdx.x >> 10;
  int t = threadIdx.x;
  short* arow = act + ((size_t)b * 1024 + n) * 192;
  if (t >= 170) {
    arow[t] = 0;
    return;
  }
  int y = n >> 5, xx = n & 31;
  const short* hb = h + (size_t)b * 1024 * 352;
  const float* wp = dw_w + t * 9;
  float s = dw_b[t];
#pragma unroll
  for (int dy = -1; dy <= 1; ++dy) {
    int yy = y + dy;
    if (yy < 0 || yy > 31) continue;
#pragma unroll
    for (int dx = -1; dx <= 1; ++dx) {
      int xw = xx + dx;
      if (xw < 0 || xw > 31) continue;
      s += wp[(dy + 1) * 3 + (dx + 1)] * bf2f(hb[(size_t)(yy * 32 + xw) * 352 + t]);
    }
  }
  float ge = 0.5f * s * (1.f + erff(s * 0.70710678118654752f));
  float gv = bf2f(hb[(size_t)n * 352 + 170 + t]);
  arow[t] = bfbits(ge * gv);
}

// ---------------------------------------------------------------------------
extern "C" void kernel_launch(void* const* d_in, const int* in_sizes, int n_in,
                              void* d_out, int out_size, void* d_ws,
                              size_t ws_size, hipStream_t stream) {
  const float* x      = (const float*)d_in[0];
  const float* ln1_g  = (const float*)d_in[1];
  const float* ln1_b  = (const float*)d_in[2];
  const float* ln2_g  = (const float*)d_in[3];
  const float* ln2_b  = (const float*)d_in[4];
  const float* qkv_w  = (const float*)d_in[5];
  const float* qkv_bn = (const float*)d_in[6];
  const float* pe_w   = (const float*)d_in[7];
  const float* pe_bn  = (const float*)d_in[8];
  const float* proj_w = (const float*)d_in[9];
  const float* proj_bn= (const float*)d_in[10];
  const float* fc1_w  = (const float*)d_in[11];
  const float* fc1_b  = (const float*)d_in[12];
  const float* dw_w   = (const float*)d_in[13];
  const float* dw_b   = (const float*)d_in[14];
  const float* fc2_w  = (const float*)d_in[15];
  const float* fc2_b  = (const float*)d_in[16];

  char* base = (char*)d_ws;
  short* xn   = (short*)(base + 0);            // 4 MB  bf16 [b][n][256]
  short* qkv  = (short*)(base + 4194304);      // 8 MB  bf16 [b][n][512]
  float* ob   = (float*)(base + 12582912);     // 8 MB  f32  [b][n][256]
  short* obf  = (short*)(base + 20971520);     // 4 MB  bf16 [b][n][256]
  float* x1   = (float*)(base + 25165824);     // 8 MB  f32  [b][n][256]
  short* xn2  = (short*)(base + 33554432);     // 4 MB  bf16 [b][n][256]
  short* hbuf = (short*)(base + 37748736);     // 5.8MB bf16 [b][n][352]
  short* act  = (short*)(base + 43515904);     // 3 MB  bf16 [b][n][192]
  short* wq   = (short*)(base + 46661632);     // 256 KB
  short* wpj  = (short*)(base + 46923776);     // 128 KB
  short* wf1  = (short*)(base + 47054848);     // 192 KB
  short* wf2  = (short*)(base + 47251456);     // 96 KB
  float* pw2  = (float*)(base + 47349760);     // 9 KB
  float* pb   = (float*)(base + 47358976);     // 1 KB
  float* bq   = (float*)(base + 47360000);     // 2 KB
  float* bpj  = (float*)(base + 47362048);     // 1 KB
  float* outp = (float*)d_out;

  hipLaunchKernelGGL(prep_kernel, dim3(1353), dim3(256), 0, stream, qkv_w,
                     qkv_bn, proj_w, proj_bn, fc1_w, fc2_w, pe_w, pe_bn, wq,
                     bq, wpj, bpj, wf1, wf2, pw2, pb);
  hipLaunchKernelGGL(ln1_kernel, dim3(512), dim3(256), 0, stream, x, ln1_g,
                     ln1_b, xn);
  // qkv GEMM: OC=512, OT=8
  hipLaunchKernelGGL((gemm2_kernel<0>), dim3(1024), dim3(256), 0, stream, xn,
                     wq, bq, nullptr, nullptr, nullptr, qkv, 512, 256, 8, 256,
                     512);
  hipLaunchKernelGGL(attn2_kernel, dim3(1024), dim3(256), 0, stream, qkv, ob);
  hipLaunchKernelGGL(pe2_kernel, dim3(8192), dim3(256), 0, stream, qkv, pw2,
                     pb, ob, obf);
  // proj GEMM: OC=256, OT=4, out x1 = proj + x
  hipLaunchKernelGGL((gemm2_kernel<1>), dim3(512), dim3(256), 0, stream, obf,
                     wpj, bpj, x, nullptr, nullptr, x1, 256, 256, 4, 256, 256);
  hipLaunchKernelGGL(ln2_kernel, dim3(512), dim3(256), 0, stream, x1, ln2_g,
                     ln2_b, xn2);
  // fc1 GEMM: OC=340 (pad 384), OT=6, out hbuf stride 352
  hipLaunchKernelGGL((gemm2_kernel<0>), dim3(768), dim3(256), 0, stream, xn2,
                     wf1, fc1_b, nullptr, nullptr, nullptr, hbuf, 340, 256, 6,
                     256, 352);
  hipLaunchKernelGGL(glu2_kernel, dim3(8192), dim3(192), 0, stream, hbuf,
                     dw_w, dw_b, act);
  // fc2 GEMM: OC=256, OT=4, K=192 (padded), out = d_out + x1 + xn2
  hipLaunchKernelGGL((gemm2_kernel<2>), dim3(512), dim3(256), 0, stream, act,
                     wf2, fc2_b, nullptr, x1, xn2, outp, 256, 192, 4, 192,
                     256);
}

// Round 5
// 182.633 us; speedup vs baseline: 5.2461x; 1.1274x over previous
//
#include <hip/hip_runtime.h>
#include <hip/hip_bf16.h>
#include <math.h>

#define EPSF 1e-5f

using short2v = __attribute__((ext_vector_type(2))) short;
using short4v = __attribute__((ext_vector_type(4))) short;
using short8 = __attribute__((ext_vector_type(8))) short;
using f32x4 = __attribute__((ext_vector_type(4))) float;

__device__ inline short bfbits(float x) {
  __hip_bfloat16 h = __float2bfloat16(x);
  return __builtin_bit_cast(short, h);
}
__device__ inline float bf2f(short s) {
  unsigned u = ((unsigned)(unsigned short)s) << 16;
  return __builtin_bit_cast(float, u);
}

// ---------------------------------------------------------------------------
// prep: fold BN into weights/bias, convert weights to bf16 (padded),
// transpose dwconv weight tables to [tap][c].
// ---------------------------------------------------------------------------
__global__ __launch_bounds__(256) void prep_kernel(
    const float* __restrict__ qkv_w, const float* __restrict__ qkv_bn,
    const float* __restrict__ proj_w, const float* __restrict__ proj_bn,
    const float* __restrict__ fc1_w, const float* __restrict__ fc2_w,
    const float* __restrict__ pe_w, const float* __restrict__ pe_bn,
    const float* __restrict__ dw_w, const float* __restrict__ dw_b,
    short* __restrict__ wq, float* __restrict__ bq, short* __restrict__ wpj,
    float* __restrict__ bpj, short* __restrict__ wf1, short* __restrict__ wf2,
    float* __restrict__ pwT, float* __restrict__ pbv, float* __restrict__ wdT,
    float* __restrict__ dbv) {
  int id = blockIdx.x * 256 + threadIdx.x;
  if (id < 131072) {
    int o = id >> 8, k = id & 255;
    float g = qkv_bn[o], bb = qkv_bn[512 + o], m = qkv_bn[1024 + o],
          v = qkv_bn[1536 + o];
    float s = g * rsqrtf(v + EPSF);
    float s2 = ((o & 63) < 16) ? 0.25f : 1.0f;
    wq[id] = bfbits(qkv_w[id] * s * s2);
    if (k == 0) bq[o] = (bb - m * s) * s2;
  } else if (id < 196608) {
    int i = id - 131072;
    int o = i >> 8, k = i & 255;
    float g = proj_bn[o], bb = proj_bn[256 + o], m = proj_bn[512 + o],
          v = proj_bn[768 + o];
    float s = g * rsqrtf(v + EPSF);
    wpj[i] = bfbits(proj_w[i] * s);
    if (k == 0) bpj[o] = bb - m * s;
  } else if (id < 294912) {
    int i = id - 196608;
    int o = i >> 8, k = i & 255;
    wf1[i] = bfbits(o < 340 ? fc1_w[o * 256 + k] : 0.f);
  } else if (id < 344064) {
    int i = id - 294912;
    int o = i / 192, k = i - o * 192;
    wf2[i] = bfbits(k < 170 ? fc2_w[o * 170 + k] : 0.f);
  } else if (id < 346368) {
    int i = id - 344064;
    int c = i & 255, tap = i >> 8;
    float g = pe_bn[c], bb = pe_bn[256 + c], m = pe_bn[512 + c],
          v = pe_bn[768 + c];
    float s = g * rsqrtf(v + EPSF);
    pwT[tap * 256 + c] = pe_w[c * 9 + tap] * s;
    if (tap == 0) pbv[c] = bb - m * s;
  } else if (id < 348096) {
    int i = id - 346368;
    int c = i % 192, tap = i / 192;
    wdT[tap * 192 + c] = (c < 170) ? dw_w[c * 9 + tap] : 0.f;
    if (tap == 0) dbv[c] = (c < 170) ? dw_b[c] : 0.f;
  }
}

// ---------------------------------------------------------------------------
// LN1: x f32 [b][c][n] -> xn bf16 channels-last [b][n][256].
// ---------------------------------------------------------------------------
__global__ __launch_bounds__(256) void ln1_kernel(
    const float* __restrict__ x, const float* __restrict__ gamma,
    const float* __restrict__ beta, short* __restrict__ xn) {
  __shared__ float s_sum[16][16];
  __shared__ float s_sq[16][16];
  int t = threadIdx.x;
  int nl = t & 15, cg = t >> 4;
  int p0 = blockIdx.x * 16;
  int b = p0 >> 10;
  int n = (p0 & 1023) + nl;
  const float* xp = x + ((size_t)b * 256 + cg * 16) * 1024 + n;
  float v[16];
  float sum = 0.f, sq = 0.f;
#pragma unroll
  for (int i = 0; i < 16; ++i) {
    float val = xp[(size_t)i * 1024];
    v[i] = val;
    sum += val;
    sq += val * val;
  }
  s_sum[cg][nl] = sum;
  s_sq[cg][nl] = sq;
  __syncthreads();
  float ts = 0.f, tq = 0.f;
#pragma unroll
  for (int g = 0; g < 16; ++g) {
    ts += s_sum[g][nl];
    tq += s_sq[g][nl];
  }
  float mu = ts * (1.f / 256.f);
  float var = tq * (1.f / 256.f) - mu * mu;
  float rs = rsqrtf(var + EPSF);
  short8 pk[2];
#pragma unroll
  for (int i = 0; i < 16; ++i) {
    int c = cg * 16 + i;
    pk[i >> 3][i & 7] = bfbits((v[i] - mu) * rs * gamma[c] + beta[c]);
  }
  short* op = xn + ((size_t)b * 1024 + n) * 256 + cg * 16;
  *reinterpret_cast<short8*>(op) = pk[0];
  *reinterpret_cast<short8*>(op + 8) = pk[1];
}

// ---------------------------------------------------------------------------
// LN2: x1 f32 CL [pos][256] -> xn2 bf16 CL.
// ---------------------------------------------------------------------------
__global__ __launch_bounds__(256) void ln2_kernel(
    const float* __restrict__ x1, const float* __restrict__ gamma,
    const float* __restrict__ beta, short* __restrict__ xn2) {
  int t = threadIdx.x;
  int lane = t & 63, w = t >> 6;
  f32x4 gv = *reinterpret_cast<const f32x4*>(&gamma[lane * 4]);
  f32x4 bv = *reinterpret_cast<const f32x4*>(&beta[lane * 4]);
#pragma unroll
  for (int it = 0; it < 4; ++it) {
    size_t pos = blockIdx.x * 16 + w * 4 + it;
    f32x4 xv = *reinterpret_cast<const f32x4*>(&x1[pos * 256 + lane * 4]);
    float s = (xv[0] + xv[1]) + (xv[2] + xv[3]);
    float q = (xv[0] * xv[0] + xv[1] * xv[1]) + (xv[2] * xv[2] + xv[3] * xv[3]);
#pragma unroll
    for (int off = 1; off < 64; off <<= 1) {
      s += __shfl_xor(s, off);
      q += __shfl_xor(q, off);
    }
    float mu = s * (1.f / 256.f);
    float var = q * (1.f / 256.f) - mu * mu;
    float rs = rsqrtf(var + EPSF);
    short4v o;
#pragma unroll
    for (int e = 0; e < 4; ++e)
      o[e] = bfbits((xv[e] - mu) * rs * gv[e] + bv[e]);
    *reinterpret_cast<short4v*>(&xn2[pos * 256 + lane * 4]) = o;
  }
}

// ---------------------------------------------------------------------------
// MFMA GEMM v3: tile 64n x 128o, BK=32, 4 waves (2o x 2n), register-
// prefetched staging. MODE 0: out bf16 CL stride RS (+bias).
// MODE 1: out f32 CL 256 (+bias + x channel-major). MODE 2: f32 CM d_out
// (+bias + x1 f32CL + xn2 bf16CL).
// ---------------------------------------------------------------------------
template <int MODE>
__global__ __launch_bounds__(256) void gemm3_kernel(
    const short* __restrict__ X, const short* __restrict__ W,
    const float* __restrict__ bias, const float* __restrict__ addCM,
    const float* __restrict__ add1CL, const short* __restrict__ add2CL,
    void* __restrict__ out, int OC, int K, int OT, int KS, int RS) {
  __shared__ short Wl[128][40];
  __shared__ short Xl[64][40];
  int bx = blockIdx.x;
  int ot = bx % OT;
  int ntb = bx / OT;
  int b = ntb >> 4;
  int n0 = (ntb & 15) * 64;
  int o0 = ot * 128;
  int t = threadIdx.x;
  int lane = t & 63, w = t >> 6;
  int wo = w >> 1, wn = w & 1;
  int g = lane >> 4, r = lane & 15;
  int srow = t >> 2, sk8 = (t & 3) * 8;
  size_t bN = (size_t)b * 1024;
  const short* Wp0 = W + (size_t)(o0 + srow) * K + sk8;
  const short* Wp1 = W + (size_t)(o0 + 64 + srow) * K + sk8;
  const short* Xp = X + (bN + n0 + srow) * KS + sk8;
  f32x4 acc[4][2] = {};
  int nsteps = K >> 5;
  short8 w0 = *reinterpret_cast<const short8*>(Wp0);
  short8 w1 = *reinterpret_cast<const short8*>(Wp1);
  short8 x0 = *reinterpret_cast<const short8*>(Xp);
  for (int ks = 0; ks < nsteps; ++ks) {
    *reinterpret_cast<short8*>(&Wl[srow][sk8]) = w0;
    *reinterpret_cast<short8*>(&Wl[64 + srow][sk8]) = w1;
    *reinterpret_cast<short8*>(&Xl[srow][sk8]) = x0;
    __syncthreads();
    if (ks + 1 < nsteps) {
      int ko = (ks + 1) << 5;
      w0 = *reinterpret_cast<const short8*>(Wp0 + ko);
      w1 = *reinterpret_cast<const short8*>(Wp1 + ko);
      x0 = *reinterpret_cast<const short8*>(Xp + ko);
    }
    short8 a[4], bb[2];
#pragma unroll
    for (int i = 0; i < 4; ++i)
      a[i] = *reinterpret_cast<const short8*>(&Wl[wo * 64 + i * 16 + r][g * 8]);
#pragma unroll
    for (int j = 0; j < 2; ++j)
      bb[j] = *reinterpret_cast<const short8*>(&Xl[wn * 32 + j * 16 + r][g * 8]);
#pragma unroll
    for (int i = 0; i < 4; ++i)
#pragma unroll
      for (int j = 0; j < 2; ++j)
        acc[i][j] = __builtin_amdgcn_mfma_f32_16x16x32_bf16(a[i], bb[j],
                                                            acc[i][j], 0, 0, 0);
    __syncthreads();
  }
#pragma unroll
  for (int i = 0; i < 4; ++i) {
#pragma unroll
    for (int j = 0; j < 2; ++j) {
      int oq = o0 + wo * 64 + i * 16 + g * 4;
      if (oq >= OC) continue;
      int n = n0 + wn * 32 + j * 16 + r;
      f32x4 bv = *reinterpret_cast<const f32x4*>(&bias[oq]);
      f32x4 res;
#pragma unroll
      for (int rr = 0; rr < 4; ++rr) res[rr] = acc[i][j][rr] + bv[rr];
      if constexpr (MODE == 0) {
        short4v s;
#pragma unroll
        for (int rr = 0; rr < 4; ++rr) s[rr] = bfbits(res[rr]);
        *reinterpret_cast<short4v*>((short*)out + (bN + n) * RS + oq) = s;
      } else if constexpr (MODE == 1) {
#pragma unroll
        for (int rr = 0; rr < 4; ++rr)
          res[rr] += addCM[((size_t)b * 256 + oq + rr) * 1024 + n];
        *reinterpret_cast<f32x4*>((float*)out + (bN + n) * 256 + oq) = res;
      } else {
        f32x4 a1v = *reinterpret_cast<const f32x4*>(&add1CL[(bN + n) * 256 + oq]);
        short4v a2v = *reinterpret_cast<const short4v*>(&add2CL[(bN + n) * 256 + oq]);
#pragma unroll
        for (int rr = 0; rr < 4; ++rr) {
          float v = res[rr] + a1v[rr] + bf2f(a2v[rr]);
          ((float*)out)[((size_t)b * 256 + oq + rr) * 1024 + n] = v;
        }
      }
    }
  }
}

// ---------------------------------------------------------------------------
// MFMA flash attention v3 + fused PE dwconv epilogue.
// Block = 4 waves x 16 queries = 64-query tile of one (b,h); 16 m-chunks
// with register-prefetched K/V staging. Epilogue: O -> bf16 LDS, then
// per-(n, d-quad) threads add dwconv3x3(V) (folded BN) and write obf bf16 CL.
// grid = B*NH*16 = 1024.
// ---------------------------------------------------------------------------
__global__ __launch_bounds__(256) void attn3_kernel(
    const short* __restrict__ qkv, const float* __restrict__ pwT,
    const float* __restrict__ pbv, short* __restrict__ obf) {
  __shared__ short Ql[64][40];
  __shared__ short Kl[64][40];
  __shared__ short Vl[32][72];
  __shared__ short Ol[64][36];
  int blk = blockIdx.x;
  int qt = blk & 15, h = (blk >> 4) & 7, b = blk >> 7;
  size_t bN = (size_t)b * 1024;
  const short* base = qkv + bN * 512 + h * 64;
  int t = threadIdx.x;
  int lane = t & 63, w = t >> 6;
  int g = lane >> 4, r = lane & 15;
  int q0 = qt * 64;
  for (int i = t; i < 64 * 16; i += 256) {
    int row = i >> 4, col = 16 + (i & 15);
    Ql[row][col] = 0;
    Kl[row][col] = 0;
  }
  {
    int qr = t >> 2, kd4 = (t & 3) * 4;
    short4v qv =
        *reinterpret_cast<const short4v*>(&base[(size_t)(q0 + qr) * 512 + kd4]);
    *reinterpret_cast<short4v*>(&Ql[qr][kd4]) = qv;
  }
  __syncthreads();
  short8 qf = *reinterpret_cast<const short8*>(&Ql[w * 16 + r][g * 8]);
  float M = -3e38f, l = 0.f;
  f32x4 O0 = {}, O1 = {};
  int mr4 = t >> 2, kd4 = (t & 3) * 4;
  int mp = t & 31, dq8 = t >> 5;
  // preload chunk 0
  short4v kreg =
      *reinterpret_cast<const short4v*>(&base[(size_t)mr4 * 512 + 16 + kd4]);
  short4v vA = *reinterpret_cast<const short4v*>(
      &base[(size_t)(2 * mp) * 512 + 32 + dq8 * 4]);
  short4v vB = *reinterpret_cast<const short4v*>(
      &base[(size_t)(2 * mp + 1) * 512 + 32 + dq8 * 4]);
  for (int ch = 0; ch < 16; ++ch) {
    *reinterpret_cast<short4v*>(&Kl[mr4][kd4]) = kreg;
#pragma unroll
    for (int e = 0; e < 4; ++e) {
      short2v p = {vA[e], vB[e]};
      *reinterpret_cast<short2v*>(&Vl[dq8 * 4 + e][2 * mp]) = p;
    }
    __syncthreads();
    if (ch + 1 < 16) {
      int m0 = (ch + 1) * 64;
      kreg = *reinterpret_cast<const short4v*>(
          &base[(size_t)(m0 + mr4) * 512 + 16 + kd4]);
      vA = *reinterpret_cast<const short4v*>(
          &base[(size_t)(m0 + 2 * mp) * 512 + 32 + dq8 * 4]);
      vB = *reinterpret_cast<const short4v*>(
          &base[(size_t)(m0 + 2 * mp + 1) * 512 + 32 + dq8 * 4]);
    }
    f32x4 s4[4];
#pragma unroll
    for (int mt = 0; mt < 4; ++mt) {
      short8 af = *reinterpret_cast<const short8*>(&Kl[mt * 16 + r][g * 8]);
      f32x4 z = {};
      s4[mt] = __builtin_amdgcn_mfma_f32_16x16x32_bf16(af, qf, z, 0, 0, 0);
    }
    float mx = -3e38f;
#pragma unroll
    for (int mt = 0; mt < 4; ++mt)
      mx = fmaxf(mx,
                 fmaxf(fmaxf(s4[mt][0], s4[mt][1]), fmaxf(s4[mt][2], s4[mt][3])));
    mx = fmaxf(mx, __shfl_xor(mx, 16));
    mx = fmaxf(mx, __shfl_xor(mx, 32));
    float Mn = fmaxf(M, mx);
    float f = __expf(M - Mn);
    M = Mn;
    float sc = 0.f;
    short8 pa[4];
#pragma unroll
    for (int mt = 0; mt < 4; ++mt) {
      float p0 = __expf(s4[mt][0] - Mn);
      float p1 = __expf(s4[mt][1] - Mn);
      float p2 = __expf(s4[mt][2] - Mn);
      float p3 = __expf(s4[mt][3] - Mn);
      sc += (p0 + p1) + (p2 + p3);
      pa[mt] = (short8){bfbits(p0), bfbits(p1), bfbits(p2), bfbits(p3),
                        0, 0, 0, 0};
    }
    sc += __shfl_xor(sc, 16);
    sc += __shfl_xor(sc, 32);
    l = l * f + sc;
#pragma unroll
    for (int rr = 0; rr < 4; ++rr) {
      float fr = __shfl(f, g * 4 + rr);
      O0[rr] *= fr;
      O1[rr] *= fr;
    }
#pragma unroll
    for (int mt = 0; mt < 4; ++mt) {
      short4v v0 = *reinterpret_cast<const short4v*>(&Vl[r][mt * 16 + g * 4]);
      short4v v1 =
          *reinterpret_cast<const short4v*>(&Vl[16 + r][mt * 16 + g * 4]);
      short8 b0 = {v0[0], v0[1], v0[2], v0[3], 0, 0, 0, 0};
      short8 b1 = {v1[0], v1[1], v1[2], v1[3], 0, 0, 0, 0};
      O0 = __builtin_amdgcn_mfma_f32_16x16x32_bf16(pa[mt], b0, O0, 0, 0, 0);
      O1 = __builtin_amdgcn_mfma_f32_16x16x32_bf16(pa[mt], b1, O1, 0, 0, 0);
    }
    __syncthreads();
  }
  // normalize, store to Ol (bf16)
#pragma unroll
  for (int rr = 0; rr < 4; ++rr) {
    float lr = __shfl(l, g * 4 + rr);
    float inv = 1.f / lr;
    int q = w * 16 + g * 4 + rr;
    Ol[q][r] = bfbits(O0[rr] * inv);
    Ol[q][16 + r] = bfbits(O1[rr] * inv);
  }
  __syncthreads();
  // fused PE epilogue: item = (q local, d-quad)
#pragma unroll
  for (int it = 0; it < 2; ++it) {
    int item = t + it * 256;
    int q = item & 63, dq = item >> 6;
    int n = q0 + q;
    int y = n >> 5, xx = n & 31;
    int cq = h * 32 + dq * 4;
    f32x4 s = *reinterpret_cast<const f32x4*>(&pbv[cq]);
#pragma unroll
    for (int dy = -1; dy <= 1; ++dy) {
      int yy = y + dy;
      if (yy < 0 || yy > 31) continue;
#pragma unroll
      for (int dx = -1; dx <= 1; ++dx) {
        int xw = xx + dx;
        if (xw < 0 || xw > 31) continue;
        int tap = (dy + 1) * 3 + (dx + 1);
        f32x4 wv = *reinterpret_cast<const f32x4*>(&pwT[tap * 256 + cq]);
        short4v vv = *reinterpret_cast<const short4v*>(
            &base[(size_t)(yy * 32 + xw) * 512 + 32 + dq * 4]);
#pragma unroll
        for (int e = 0; e < 4; ++e) s[e] += wv[e] * bf2f(vv[e]);
      }
    }
    short4v ov = *reinterpret_cast<const short4v*>(&Ol[q][dq * 4]);
    short4v res;
#pragma unroll
    for (int e = 0; e < 4; ++e) res[e] = bfbits(bf2f(ov[e]) + s[e]);
    *reinterpret_cast<short4v*>(&obf[(bN + n) * 256 + cq]) = res;
  }
}

// ---------------------------------------------------------------------------
// GLU v3 (channels-last, vectorized): act[n][192] = bf16(gelu(dwconv(a)+b)*g).
// Block 256 thr = 16 positions x 16 channel-groups of 12. grid 512.
// ---------------------------------------------------------------------------
__global__ __launch_bounds__(256) void glu3_kernel(
    const short* __restrict__ h, const float* __restrict__ wdT,
    const float* __restrict__ dbv, short* __restrict__ act) {
  int t = threadIdx.x;
  int pos = blockIdx.x * 16 + (t >> 4);
  int c0 = (t & 15) * 12;
  int n = pos & 1023;
  int b = pos >> 10;
  int y = n >> 5, xx = n & 31;
  const short* hb = h + (size_t)b * 1024 * 352;
  float s[12];
#pragma unroll
  for (int e = 0; e < 12; ++e) s[e] = dbv[c0 + e];
#pragma unroll
  for (int dy = -1; dy <= 1; ++dy) {
    int yy = y + dy;
    if (yy < 0 || yy > 31) continue;
#pragma unroll
    for (int dx = -1; dx <= 1; ++dx) {
      int xw = xx + dx;
      if (xw < 0 || xw > 31) continue;
      int tap = (dy + 1) * 3 + (dx + 1);
      const float* wp = wdT + tap * 192 + c0;
      const short* ap = hb + (size_t)(yy * 32 + xw) * 352 + c0;
#pragma unroll
      for (int v4 = 0; v4 < 3; ++v4) {
        short4v av = *reinterpret_cast<const short4v*>(ap + v4 * 4);
        f32x4 wv = *reinterpret_cast<const f32x4*>(wp + v4 * 4);
#pragma unroll
        for (int e = 0; e < 4; ++e) s[v4 * 4 + e] += wv[e] * bf2f(av[e]);
      }
    }
  }
  const short* gp = hb + (size_t)n * 352 + 170 + c0;
  short* arow = act + ((size_t)b * 1024 + n) * 192 + c0;
#pragma unroll
  for (int v4 = 0; v4 < 3; ++v4) {
    short4v res;
#pragma unroll
    for (int e = 0; e < 4; ++e) {
      float sv = s[v4 * 4 + e];
      float ge = 0.5f * sv * (1.f + erff(sv * 0.70710678118654752f));
      res[e] = bfbits(ge * bf2f(gp[v4 * 4 + e]));
    }
    *reinterpret_cast<short4v*>(arow + v4 * 4) = res;
  }
}

// ---------------------------------------------------------------------------
extern "C" void kernel_launch(void* const* d_in, const int* in_sizes, int n_in,
                              void* d_out, int out_size, void* d_ws,
                              size_t ws_size, hipStream_t stream) {
  const float* x      = (const float*)d_in[0];
  const float* ln1_g  = (const float*)d_in[1];
  const float* ln1_b  = (const float*)d_in[2];
  const float* ln2_g  = (const float*)d_in[3];
  const float* ln2_b  = (const float*)d_in[4];
  const float* qkv_w  = (const float*)d_in[5];
  const float* qkv_bn = (const float*)d_in[6];
  const float* pe_w   = (const float*)d_in[7];
  const float* pe_bn  = (const float*)d_in[8];
  const float* proj_w = (const float*)d_in[9];
  const float* proj_bn= (const float*)d_in[10];
  const float* fc1_w  = (const float*)d_in[11];
  const float* fc1_b  = (const float*)d_in[12];
  const float* dw_w   = (const float*)d_in[13];
  const float* dw_b   = (const float*)d_in[14];
  const float* fc2_w  = (const float*)d_in[15];
  const float* fc2_b  = (const float*)d_in[16];

  char* base = (char*)d_ws;
  short* xn   = (short*)(base + 0);          // 4 MiB bf16 [b][n][256]
  short* qkv  = (short*)(base + 4194304);    // 8 MiB bf16 [b][n][512]
  short* obf  = (short*)(base + 12582912);   // 4 MiB bf16 [b][n][256]
  float* x1   = (float*)(base + 16777216);   // 8 MiB f32  [b][n][256]
  short* xn2  = (short*)(base + 25165824);   // 4 MiB bf16 [b][n][256]
  short* hbuf = (short*)(base + 29360128);   // 5.5 MiB + pad bf16 [b][n][352]
  short* act  = (short*)(base + 35131392);   // 3 MiB bf16 [b][n][192]
  short* wq   = (short*)(base + 38277120);
  short* wpj  = (short*)(base + 38539264);
  short* wf1  = (short*)(base + 38670336);
  short* wf2  = (short*)(base + 38866944);
  float* pwT  = (float*)(base + 38965248);
  float* pbv  = (float*)(base + 38974464);
  float* wdT  = (float*)(base + 38975488);
  float* dbv  = (float*)(base + 38982400);
  float* bq   = (float*)(base + 38983168);
  float* bpj  = (float*)(base + 38985216);
  float* outp = (float*)d_out;

  hipLaunchKernelGGL(prep_kernel, dim3(1360), dim3(256), 0, stream, qkv_w,
                     qkv_bn, proj_w, proj_bn, fc1_w, fc2_w, pe_w, pe_bn, dw_w,
                     dw_b, wq, bq, wpj, bpj, wf1, wf2, pwT, pbv, wdT, dbv);
  hipLaunchKernelGGL(ln1_kernel, dim3(512), dim3(256), 0, stream, x, ln1_g,
                     ln1_b, xn);
  // qkv GEMM: OC=512, OT=4
  hipLaunchKernelGGL((gemm3_kernel<0>), dim3(512), dim3(256), 0, stream, xn,
                     wq, bq, nullptr, nullptr, nullptr, qkv, 512, 256, 4, 256,
                     512);
  // attention + PE fused
  hipLaunchKernelGGL(attn3_kernel, dim3(1024), dim3(256), 0, stream, qkv, pwT,
                     pbv, obf);
  // proj GEMM: OC=256, OT=2, out x1 = proj + x
  hipLaunchKernelGGL((gemm3_kernel<1>), dim3(256), dim3(256), 0, stream, obf,
                     wpj, bpj, x, nullptr, nullptr, x1, 256, 256, 2, 256, 256);
  hipLaunchKernelGGL(ln2_kernel, dim3(512), dim3(256), 0, stream, x1, ln2_g,
                     ln2_b, xn2);
  // fc1 GEMM: OC=340 (pad 384), OT=3, out hbuf stride 352
  hipLaunchKernelGGL((gemm3_kernel<0>), dim3(384), dim3(256), 0, stream, xn2,
                     wf1, fc1_b, nullptr, nullptr, nullptr, hbuf, 340, 256, 3,
                     256, 352);
  hipLaunchKernelGGL(glu3_kernel, dim3(512), dim3(256), 0, stream, hbuf, wdT,
                     dbv, act);
  // fc2 GEMM: OC=256, K=192, OT=2, out = d_out + x1 + xn2
  hipLaunchKernelGGL((gemm3_kernel<2>), dim3(256), dim3(256), 0, stream, act,
                     wf2, fc2_b, nullptr, x1, xn2, outp, 256, 192, 2, 192,
                     256);
}

// Round 6
// 177.571 us; speedup vs baseline: 5.3956x; 1.0285x over previous
//
#include <hip/hip_runtime.h>
#include <hip/hip_bf16.h>
#include <math.h>

#define EPSF 1e-5f

using short2v = __attribute__((ext_vector_type(2))) short;
using short4v = __attribute__((ext_vector_type(4))) short;
using short8 = __attribute__((ext_vector_type(8))) short;
using f32x4 = __attribute__((ext_vector_type(4))) float;

__device__ inline short bfbits(float x) {
  __hip_bfloat16 h = __float2bfloat16(x);
  return __builtin_bit_cast(short, h);
}
__device__ inline float bf2f(short s) {
  unsigned u = ((unsigned)(unsigned short)s) << 16;
  return __builtin_bit_cast(float, u);
}

// ---------------------------------------------------------------------------
// prep: fold BN into weights/bias, convert weights to bf16 (padded),
// transpose dwconv weight tables to [tap][c]. Q rows also absorb log2(e)
// so attention can use exp2 directly.
// ---------------------------------------------------------------------------
__global__ __launch_bounds__(256) void prep_kernel(
    const float* __restrict__ qkv_w, const float* __restrict__ qkv_bn,
    const float* __restrict__ proj_w, const float* __restrict__ proj_bn,
    const float* __restrict__ fc1_w, const float* __restrict__ fc2_w,
    const float* __restrict__ pe_w, const float* __restrict__ pe_bn,
    const float* __restrict__ dw_w, const float* __restrict__ dw_b,
    short* __restrict__ wq, float* __restrict__ bq, short* __restrict__ wpj,
    float* __restrict__ bpj, short* __restrict__ wf1, short* __restrict__ wf2,
    float* __restrict__ pwT, float* __restrict__ pbv, float* __restrict__ wdT,
    float* __restrict__ dbv) {
  int id = blockIdx.x * 256 + threadIdx.x;
  if (id < 131072) {
    int o = id >> 8, k = id & 255;
    float g = qkv_bn[o], bb = qkv_bn[512 + o], m = qkv_bn[1024 + o],
          v = qkv_bn[1536 + o];
    float s = g * rsqrtf(v + EPSF);
    float s2 = ((o & 63) < 16) ? 0.25f * 1.44269504088896f : 1.0f;
    wq[id] = bfbits(qkv_w[id] * s * s2);
    if (k == 0) bq[o] = (bb - m * s) * s2;
  } else if (id < 196608) {
    int i = id - 131072;
    int o = i >> 8, k = i & 255;
    float g = proj_bn[o], bb = proj_bn[256 + o], m = proj_bn[512 + o],
          v = proj_bn[768 + o];
    float s = g * rsqrtf(v + EPSF);
    wpj[i] = bfbits(proj_w[i] * s);
    if (k == 0) bpj[o] = bb - m * s;
  } else if (id < 294912) {
    int i = id - 196608;
    int o = i >> 8, k = i & 255;
    wf1[i] = bfbits(o < 340 ? fc1_w[o * 256 + k] : 0.f);
  } else if (id < 344064) {
    int i = id - 294912;
    int o = i / 192, k = i - o * 192;
    wf2[i] = bfbits(k < 170 ? fc2_w[o * 170 + k] : 0.f);
  } else if (id < 346368) {
    int i = id - 344064;
    int c = i & 255, tap = i >> 8;
    float g = pe_bn[c], bb = pe_bn[256 + c], m = pe_bn[512 + c],
          v = pe_bn[768 + c];
    float s = g * rsqrtf(v + EPSF);
    pwT[tap * 256 + c] = pe_w[c * 9 + tap] * s;
    if (tap == 0) pbv[c] = bb - m * s;
  } else if (id < 348096) {
    int i = id - 346368;
    int c = i % 192, tap = i / 192;
    wdT[tap * 192 + c] = (c < 170) ? dw_w[c * 9 + tap] : 0.f;
    if (tap == 0) dbv[c] = (c < 170) ? dw_b[c] : 0.f;
  }
}

// ---------------------------------------------------------------------------
// LN1: x f32 [b][c][n] -> xn bf16 channels-last [b][n][256].
// ---------------------------------------------------------------------------
__global__ __launch_bounds__(256) void ln1_kernel(
    const float* __restrict__ x, const float* __restrict__ gamma,
    const float* __restrict__ beta, short* __restrict__ xn) {
  __shared__ float s_sum[16][16];
  __shared__ float s_sq[16][16];
  int t = threadIdx.x;
  int nl = t & 15, cg = t >> 4;
  int p0 = blockIdx.x * 16;
  int b = p0 >> 10;
  int n = (p0 & 1023) + nl;
  const float* xp = x + ((size_t)b * 256 + cg * 16) * 1024 + n;
  float v[16];
  float sum = 0.f, sq = 0.f;
#pragma unroll
  for (int i = 0; i < 16; ++i) {
    float val = xp[(size_t)i * 1024];
    v[i] = val;
    sum += val;
    sq += val * val;
  }
  s_sum[cg][nl] = sum;
  s_sq[cg][nl] = sq;
  __syncthreads();
  float ts = 0.f, tq = 0.f;
#pragma unroll
  for (int g = 0; g < 16; ++g) {
    ts += s_sum[g][nl];
    tq += s_sq[g][nl];
  }
  float mu = ts * (1.f / 256.f);
  float var = tq * (1.f / 256.f) - mu * mu;
  float rs = rsqrtf(var + EPSF);
  short8 pk[2];
#pragma unroll
  for (int i = 0; i < 16; ++i) {
    int c = cg * 16 + i;
    pk[i >> 3][i & 7] = bfbits((v[i] - mu) * rs * gamma[c] + beta[c]);
  }
  short* op = xn + ((size_t)b * 1024 + n) * 256 + cg * 16;
  *reinterpret_cast<short8*>(op) = pk[0];
  *reinterpret_cast<short8*>(op + 8) = pk[1];
}

// ---------------------------------------------------------------------------
// LN2: x1 f32 CL [pos][256] -> xn2 bf16 CL.
// ---------------------------------------------------------------------------
__global__ __launch_bounds__(256) void ln2_kernel(
    const float* __restrict__ x1, const float* __restrict__ gamma,
    const float* __restrict__ beta, short* __restrict__ xn2) {
  int t = threadIdx.x;
  int lane = t & 63, w = t >> 6;
  f32x4 gv = *reinterpret_cast<const f32x4*>(&gamma[lane * 4]);
  f32x4 bv = *reinterpret_cast<const f32x4*>(&beta[lane * 4]);
#pragma unroll
  for (int it = 0; it < 4; ++it) {
    size_t pos = blockIdx.x * 16 + w * 4 + it;
    f32x4 xv = *reinterpret_cast<const f32x4*>(&x1[pos * 256 + lane * 4]);
    float s = (xv[0] + xv[1]) + (xv[2] + xv[3]);
    float q = (xv[0] * xv[0] + xv[1] * xv[1]) + (xv[2] * xv[2] + xv[3] * xv[3]);
#pragma unroll
    for (int off = 1; off < 64; off <<= 1) {
      s += __shfl_xor(s, off);
      q += __shfl_xor(q, off);
    }
    float mu = s * (1.f / 256.f);
    float var = q * (1.f / 256.f) - mu * mu;
    float rs = rsqrtf(var + EPSF);
    short4v o;
#pragma unroll
    for (int e = 0; e < 4; ++e)
      o[e] = bfbits((xv[e] - mu) * rs * gv[e] + bv[e]);
    *reinterpret_cast<short4v*>(&xn2[pos * 256 + lane * 4]) = o;
  }
}

// ---------------------------------------------------------------------------
// MFMA GEMM v4: tile 64n x 128o, BK=64, 4 waves (2o x 2n), register-
// prefetched staging, 2 barriers per k-step (halved vs BK=32).
// MODE 0: out bf16 CL stride RS (+bias). MODE 1: out f32 CL 256 (+bias +
// x channel-major). MODE 2: f32 CM d_out (+bias + x1 f32CL + xn2 bf16CL).
// ---------------------------------------------------------------------------
template <int MODE>
__global__ __launch_bounds__(256) void gemm4_kernel(
    const short* __restrict__ X, const short* __restrict__ W,
    const float* __restrict__ bias, const float* __restrict__ addCM,
    const float* __restrict__ add1CL, const short* __restrict__ add2CL,
    void* __restrict__ out, int OC, int K, int OT, int KS, int RS) {
  __shared__ short Wl[128][72];
  __shared__ short Xl[64][72];
  int bx = blockIdx.x;
  int ot = bx % OT;
  int ntb = bx / OT;
  int b = ntb >> 4;
  int n0 = (ntb & 15) * 64;
  int o0 = ot * 128;
  int t = threadIdx.x;
  int lane = t & 63, w = t >> 6;
  int wo = w >> 1, wn = w & 1;
  int g = lane >> 4, r = lane & 15;
  int rw = t >> 1, cw = (t & 1) * 32;
  int rx = t >> 2, cx = (t & 3) * 16;
  size_t bN = (size_t)b * 1024;
  const short* Wp = W + (size_t)(o0 + rw) * K + cw;
  const short* Xp = X + (bN + n0 + rx) * KS + cx;
  f32x4 acc[4][2] = {};
  int nsteps = K >> 6;
  short8 wreg[4], xreg[2];
#pragma unroll
  for (int e = 0; e < 4; ++e)
    wreg[e] = *reinterpret_cast<const short8*>(Wp + e * 8);
#pragma unroll
  for (int e = 0; e < 2; ++e)
    xreg[e] = *reinterpret_cast<const short8*>(Xp + e * 8);
  for (int ks = 0; ks < nsteps; ++ks) {
#pragma unroll
    for (int e = 0; e < 4; ++e)
      *reinterpret_cast<short8*>(&Wl[rw][cw + e * 8]) = wreg[e];
#pragma unroll
    for (int e = 0; e < 2; ++e)
      *reinterpret_cast<short8*>(&Xl[rx][cx + e * 8]) = xreg[e];
    __syncthreads();
    if (ks + 1 < nsteps) {
      int ko = (ks + 1) << 6;
#pragma unroll
      for (int e = 0; e < 4; ++e)
        wreg[e] = *reinterpret_cast<const short8*>(Wp + ko + e * 8);
#pragma unroll
      for (int e = 0; e < 2; ++e)
        xreg[e] = *reinterpret_cast<const short8*>(Xp + ko + e * 8);
    }
#pragma unroll
    for (int kk = 0; kk < 2; ++kk) {
      short8 a[4], bb[2];
#pragma unroll
      for (int i = 0; i < 4; ++i)
        a[i] = *reinterpret_cast<const short8*>(
            &Wl[wo * 64 + i * 16 + r][kk * 32 + g * 8]);
#pragma unroll
      for (int j = 0; j < 2; ++j)
        bb[j] = *reinterpret_cast<const short8*>(
            &Xl[wn * 32 + j * 16 + r][kk * 32 + g * 8]);
#pragma unroll
      for (int i = 0; i < 4; ++i)
#pragma unroll
        for (int j = 0; j < 2; ++j)
          acc[i][j] = __builtin_amdgcn_mfma_f32_16x16x32_bf16(
              a[i], bb[j], acc[i][j], 0, 0, 0);
    }
    __syncthreads();
  }
#pragma unroll
  for (int i = 0; i < 4; ++i) {
#pragma unroll
    for (int j = 0; j < 2; ++j) {
      int oq = o0 + wo * 64 + i * 16 + g * 4;
      if (oq >= OC) continue;
      int n = n0 + wn * 32 + j * 16 + r;
      f32x4 bv = *reinterpret_cast<const f32x4*>(&bias[oq]);
      f32x4 res;
#pragma unroll
      for (int rr = 0; rr < 4; ++rr) res[rr] = acc[i][j][rr] + bv[rr];
      if constexpr (MODE == 0) {
        short4v s;
#pragma unroll
        for (int rr = 0; rr < 4; ++rr) s[rr] = bfbits(res[rr]);
        *reinterpret_cast<short4v*>((short*)out + (bN + n) * RS + oq) = s;
      } else if constexpr (MODE == 1) {
#pragma unroll
        for (int rr = 0; rr < 4; ++rr)
          res[rr] += addCM[((size_t)b * 256 + oq + rr) * 1024 + n];
        *reinterpret_cast<f32x4*>((float*)out + (bN + n) * 256 + oq) = res;
      } else {
        f32x4 a1v = *reinterpret_cast<const f32x4*>(&add1CL[(bN + n) * 256 + oq]);
        short4v a2v = *reinterpret_cast<const short4v*>(&add2CL[(bN + n) * 256 + oq]);
#pragma unroll
        for (int rr = 0; rr < 4; ++rr) {
          float v = res[rr] + a1v[rr] + bf2f(a2v[rr]);
          ((float*)out)[((size_t)b * 256 + oq + rr) * 1024 + n] = v;
        }
      }
    }
  }
}

// ---------------------------------------------------------------------------
// MFMA flash attention v4 + fused PE epilogue.
// XCD swizzle: h = blk&7 (fastest) so all 16 q-tiles of one (b,h) land on
// one XCD (K/V L2-resident). Double-buffered K/V LDS: 1 barrier per chunk,
// global loads issued at top of iteration, LDS writes after compute (T14).
// Softmax in exp2 domain (log2e folded into Q); T13 defer-max rescale.
// grid = 1024.
// ---------------------------------------------------------------------------
__global__ __launch_bounds__(256) void attn4_kernel(
    const short* __restrict__ qkv, const float* __restrict__ pwT,
    const float* __restrict__ pbv, short* __restrict__ obf) {
  __shared__ short Ql[64][40];
  __shared__ short Kl[2][64][40];
  __shared__ short Vl[2][32][72];
  __shared__ short Ol[64][36];
  int blk = blockIdx.x;
  int h = blk & 7, qt = (blk >> 3) & 15, b = blk >> 7;
  size_t bN = (size_t)b * 1024;
  const short* base = qkv + bN * 512 + h * 64;
  int t = threadIdx.x;
  int lane = t & 63, w = t >> 6;
  int g = lane >> 4, r = lane & 15;
  int q0 = qt * 64;
  for (int i = t; i < 64 * 16; i += 256) {
    int row = i >> 4, col = 16 + (i & 15);
    Ql[row][col] = 0;
    Kl[0][row][col] = 0;
    Kl[1][row][col] = 0;
  }
  {
    int qr = t >> 2, kd4 = (t & 3) * 4;
    short4v qv =
        *reinterpret_cast<const short4v*>(&base[(size_t)(q0 + qr) * 512 + kd4]);
    *reinterpret_cast<short4v*>(&Ql[qr][kd4]) = qv;
  }
  int mr4 = t >> 2, kd4 = (t & 3) * 4;
  int mp = t & 31, dq8 = t >> 5;
  // preload + stage chunk 0 into buffer 0
  short4v kreg =
      *reinterpret_cast<const short4v*>(&base[(size_t)mr4 * 512 + 16 + kd4]);
  short4v vA = *reinterpret_cast<const short4v*>(
      &base[(size_t)(2 * mp) * 512 + 32 + dq8 * 4]);
  short4v vB = *reinterpret_cast<const short4v*>(
      &base[(size_t)(2 * mp + 1) * 512 + 32 + dq8 * 4]);
  *reinterpret_cast<short4v*>(&Kl[0][mr4][kd4]) = kreg;
#pragma unroll
  for (int e = 0; e < 4; ++e) {
    short2v p = {vA[e], vB[e]};
    *reinterpret_cast<short2v*>(&Vl[0][dq8 * 4 + e][2 * mp]) = p;
  }
  __syncthreads();
  short8 qf = *reinterpret_cast<const short8*>(&Ql[w * 16 + r][g * 8]);
  float M = -3e38f, l = 0.f;
  f32x4 O0 = {}, O1 = {};
  for (int ch = 0; ch < 16; ++ch) {
    int cur = ch & 1;
    if (ch + 1 < 16) {
      int m0 = (ch + 1) * 64;
      kreg = *reinterpret_cast<const short4v*>(
          &base[(size_t)(m0 + mr4) * 512 + 16 + kd4]);
      vA = *reinterpret_cast<const short4v*>(
          &base[(size_t)(m0 + 2 * mp) * 512 + 32 + dq8 * 4]);
      vB = *reinterpret_cast<const short4v*>(
          &base[(size_t)(m0 + 2 * mp + 1) * 512 + 32 + dq8 * 4]);
    }
    f32x4 s4[4];
#pragma unroll
    for (int mt = 0; mt < 4; ++mt) {
      short8 af = *reinterpret_cast<const short8*>(&Kl[cur][mt * 16 + r][g * 8]);
      f32x4 z = {};
      s4[mt] = __builtin_amdgcn_mfma_f32_16x16x32_bf16(af, qf, z, 0, 0, 0);
    }
    float pm = -3e38f;
#pragma unroll
    for (int mt = 0; mt < 4; ++mt)
      pm = fmaxf(pm,
                 fmaxf(fmaxf(s4[mt][0], s4[mt][1]), fmaxf(s4[mt][2], s4[mt][3])));
    pm = fmaxf(pm, __shfl_xor(pm, 16));
    pm = fmaxf(pm, __shfl_xor(pm, 32));
    bool full = !__all(pm - M <= 8.f);  // T13: defer rescale
    float Mn = full ? fmaxf(M, pm) : M;
    float f = full ? exp2f(M - Mn) : 1.f;
    M = Mn;
    float sc = 0.f;
    short8 pa[4];
#pragma unroll
    for (int mt = 0; mt < 4; ++mt) {
      float p0 = exp2f(s4[mt][0] - Mn);
      float p1 = exp2f(s4[mt][1] - Mn);
      float p2 = exp2f(s4[mt][2] - Mn);
      float p3 = exp2f(s4[mt][3] - Mn);
      sc += (p0 + p1) + (p2 + p3);
      pa[mt] = (short8){bfbits(p0), bfbits(p1), bfbits(p2), bfbits(p3),
                        0, 0, 0, 0};
    }
    sc += __shfl_xor(sc, 16);
    sc += __shfl_xor(sc, 32);
    l = l * f + sc;
    if (full) {
#pragma unroll
      for (int rr = 0; rr < 4; ++rr) {
        float fr = __shfl(f, g * 4 + rr);
        O0[rr] *= fr;
        O1[rr] *= fr;
      }
    }
#pragma unroll
    for (int mt = 0; mt < 4; ++mt) {
      short4v v0 = *reinterpret_cast<const short4v*>(&Vl[cur][r][mt * 16 + g * 4]);
      short4v v1 =
          *reinterpret_cast<const short4v*>(&Vl[cur][16 + r][mt * 16 + g * 4]);
      short8 b0 = {v0[0], v0[1], v0[2], v0[3], 0, 0, 0, 0};
      short8 b1 = {v1[0], v1[1], v1[2], v1[3], 0, 0, 0, 0};
      O0 = __builtin_amdgcn_mfma_f32_16x16x32_bf16(pa[mt], b0, O0, 0, 0, 0);
      O1 = __builtin_amdgcn_mfma_f32_16x16x32_bf16(pa[mt], b1, O1, 0, 0, 0);
    }
    if (ch + 1 < 16) {
      int nxt = cur ^ 1;
      *reinterpret_cast<short4v*>(&Kl[nxt][mr4][kd4]) = kreg;
#pragma unroll
      for (int e = 0; e < 4; ++e) {
        short2v p = {vA[e], vB[e]};
        *reinterpret_cast<short2v*>(&Vl[nxt][dq8 * 4 + e][2 * mp]) = p;
      }
    }
    __syncthreads();
  }
  // normalize, store to Ol (bf16)
#pragma unroll
  for (int rr = 0; rr < 4; ++rr) {
    float lr = __shfl(l, g * 4 + rr);
    float inv = 1.f / lr;
    int q = w * 16 + g * 4 + rr;
    Ol[q][r] = bfbits(O0[rr] * inv);
    Ol[q][16 + r] = bfbits(O1[rr] * inv);
  }
  __syncthreads();
  // fused PE epilogue: item = (q local, d-quad)
#pragma unroll
  for (int it = 0; it < 2; ++it) {
    int item = t + it * 256;
    int q = item & 63, dq = item >> 6;
    int n = q0 + q;
    int y = n >> 5, xx = n & 31;
    int cq = h * 32 + dq * 4;
    f32x4 s = *reinterpret_cast<const f32x4*>(&pbv[cq]);
#pragma unroll
    for (int dy = -1; dy <= 1; ++dy) {
      int yy = y + dy;
      if (yy < 0 || yy > 31) continue;
#pragma unroll
      for (int dx = -1; dx <= 1; ++dx) {
        int xw = xx + dx;
        if (xw < 0 || xw > 31) continue;
        int tap = (dy + 1) * 3 + (dx + 1);
        f32x4 wv = *reinterpret_cast<const f32x4*>(&pwT[tap * 256 + cq]);
        short4v vv = *reinterpret_cast<const short4v*>(
            &base[(size_t)(yy * 32 + xw) * 512 + 32 + dq * 4]);
#pragma unroll
        for (int e = 0; e < 4; ++e) s[e] += wv[e] * bf2f(vv[e]);
      }
    }
    short4v ov = *reinterpret_cast<const short4v*>(&Ol[q][dq * 4]);
    short4v res;
#pragma unroll
    for (int e = 0; e < 4; ++e) res[e] = bfbits(bf2f(ov[e]) + s[e]);
    *reinterpret_cast<short4v*>(&obf[(bN + n) * 256 + cq]) = res;
  }
}

// ---------------------------------------------------------------------------
// GLU v3 (channels-last, vectorized): act[n][192] = bf16(gelu(dwconv(a)+b)*g).
// ---------------------------------------------------------------------------
__global__ __launch_bounds__(256) void glu3_kernel(
    const short* __restrict__ h, const float* __restrict__ wdT,
    const float* __restrict__ dbv, short* __restrict__ act) {
  int t = threadIdx.x;
  int pos = blockIdx.x * 16 + (t >> 4);
  int c0 = (t & 15) * 12;
  int n = pos & 1023;
  int b = pos >> 10;
  int y = n >> 5, xx = n & 31;
  const short* hb = h + (size_t)b * 1024 * 352;
  float s[12];
#pragma unroll
  for (int e = 0; e < 12; ++e) s[e] = dbv[c0 + e];
#pragma unroll
  for (int dy = -1; dy <= 1; ++dy) {
    int yy = y + dy;
    if (yy < 0 || yy > 31) continue;
#pragma unroll
    for (int dx = -1; dx <= 1; ++dx) {
      int xw = xx + dx;
      if (xw < 0 || xw > 31) continue;
      int tap = (dy + 1) * 3 + (dx + 1);
      const float* wp = wdT + tap * 192 + c0;
      const short* ap = hb + (size_t)(yy * 32 + xw) * 352 + c0;
#pragma unroll
      for (int v4 = 0; v4 < 3; ++v4) {
        short4v av = *reinterpret_cast<const short4v*>(ap + v4 * 4);
        f32x4 wv = *reinterpret_cast<const f32x4*>(wp + v4 * 4);
#pragma unroll
        for (int e = 0; e < 4; ++e) s[v4 * 4 + e] += wv[e] * bf2f(av[e]);
      }
    }
  }
  const short* gp = hb + (size_t)n * 352 + 170 + c0;
  short* arow = act + ((size_t)b * 1024 + n) * 192 + c0;
#pragma unroll
  for (int v4 = 0; v4 < 3; ++v4) {
    short4v res;
#pragma unroll
    for (int e = 0; e < 4; ++e) {
      float sv = s[v4 * 4 + e];
      float ge = 0.5f * sv * (1.f + erff(sv * 0.70710678118654752f));
      res[e] = bfbits(ge * bf2f(gp[v4 * 4 + e]));
    }
    *reinterpret_cast<short4v*>(arow + v4 * 4) = res;
  }
}

// ---------------------------------------------------------------------------
extern "C" void kernel_launch(void* const* d_in, const int* in_sizes, int n_in,
                              void* d_out, int out_size, void* d_ws,
                              size_t ws_size, hipStream_t stream) {
  const float* x      = (const float*)d_in[0];
  const float* ln1_g  = (const float*)d_in[1];
  const float* ln1_b  = (const float*)d_in[2];
  const float* ln2_g  = (const float*)d_in[3];
  const float* ln2_b  = (const float*)d_in[4];
  const float* qkv_w  = (const float*)d_in[5];
  const float* qkv_bn = (const float*)d_in[6];
  const float* pe_w   = (const float*)d_in[7];
  const float* pe_bn  = (const float*)d_in[8];
  const float* proj_w = (const float*)d_in[9];
  const float* proj_bn= (const float*)d_in[10];
  const float* fc1_w  = (const float*)d_in[11];
  const float* fc1_b  = (const float*)d_in[12];
  const float* dw_w   = (const float*)d_in[13];
  const float* dw_b   = (const float*)d_in[14];
  const float* fc2_w  = (const float*)d_in[15];
  const float* fc2_b  = (const float*)d_in[16];

  char* base = (char*)d_ws;
  short* xn   = (short*)(base + 0);          // 4 MiB bf16 [b][n][256]
  short* qkv  = (short*)(base + 4194304);    // 8 MiB bf16 [b][n][512]
  short* obf  = (short*)(base + 12582912);   // 4 MiB bf16 [b][n][256]
  float* x1   = (float*)(base + 16777216);   // 8 MiB f32  [b][n][256]
  short* xn2  = (short*)(base + 25165824);   // 4 MiB bf16 [b][n][256]
  short* hbuf = (short*)(base + 29360128);   // 5.5 MiB + pad bf16 [b][n][352]
  short* act  = (short*)(base + 35131392);   // 3 MiB bf16 [b][n][192]
  short* wq   = (short*)(base + 38277120);
  short* wpj  = (short*)(base + 38539264);
  short* wf1  = (short*)(base + 38670336);
  short* wf2  = (short*)(base + 38866944);
  float* pwT  = (float*)(base + 38965248);
  float* pbv  = (float*)(base + 38974464);
  float* wdT  = (float*)(base + 38975488);
  float* dbv  = (float*)(base + 38982400);
  float* bq   = (float*)(base + 38983168);
  float* bpj  = (float*)(base + 38985216);
  float* outp = (float*)d_out;

  hipLaunchKernelGGL(prep_kernel, dim3(1360), dim3(256), 0, stream, qkv_w,
                     qkv_bn, proj_w, proj_bn, fc1_w, fc2_w, pe_w, pe_bn, dw_w,
                     dw_b, wq, bq, wpj, bpj, wf1, wf2, pwT, pbv, wdT, dbv);
  hipLaunchKernelGGL(ln1_kernel, dim3(512), dim3(256), 0, stream, x, ln1_g,
                     ln1_b, xn);
  // qkv GEMM: OC=512, OT=4
  hipLaunchKernelGGL((gemm4_kernel<0>), dim3(512), dim3(256), 0, stream, xn,
                     wq, bq, nullptr, nullptr, nullptr, qkv, 512, 256, 4, 256,
                     512);
  // attention + PE fused
  hipLaunchKernelGGL(attn4_kernel, dim3(1024), dim3(256), 0, stream, qkv, pwT,
                     pbv, obf);
  // proj GEMM: OC=256, OT=2, out x1 = proj + x
  hipLaunchKernelGGL((gemm4_kernel<1>), dim3(256), dim3(256), 0, stream, obf,
                     wpj, bpj, x, nullptr, nullptr, x1, 256, 256, 2, 256, 256);
  hipLaunchKernelGGL(ln2_kernel, dim3(512), dim3(256), 0, stream, x1, ln2_g,
                     ln2_b, xn2);
  // fc1 GEMM: OC=340 (pad 384), OT=3, out hbuf stride 352
  hipLaunchKernelGGL((gemm4_kernel<0>), dim3(384), dim3(256), 0, stream, xn2,
                     wf1, fc1_b, nullptr, nullptr, nullptr, hbuf, 340, 256, 3,
                     256, 352);
  hipLaunchKernelGGL(glu3_kernel, dim3(512), dim3(256), 0, stream, hbuf, wdT,
                     dbv, act);
  // fc2 GEMM: OC=256, K=192, OT=2, out = d_out + x1 + xn2
  hipLaunchKernelGGL((gemm4_kernel<2>), dim3(256), dim3(256), 0, stream, act,
                     wf2, fc2_b, nullptr, x1, xn2, outp, 256, 192, 2, 192,
                     256);
}